// Round 13
// baseline (579.249 us; speedup 1.0000x reference)
//
#include <hip/hip_runtime.h>
#include <stdint.h>

// ---------------------------------------------------------------------------
// MultiHeadedAttention (4-scale patch attention) for MI355X / gfx950
// R13: fix R12's zero-vs-atomicAdd race (k_mask back to its own launch,
//      after k_prep's zeroing). Keep R12 conv (256x256 reg-staged GEMM,
//      BK=64 tap-major) and scores z-split x2.
// ---------------------------------------------------------------------------

typedef __attribute__((ext_vector_type(8))) short short8;
typedef __attribute__((ext_vector_type(4))) float floatx4;
typedef __attribute__((ext_vector_type(4))) unsigned int uintx4;

#define DEV static __device__ __forceinline__

DEV unsigned short f2bf(float f) {
  unsigned u = __builtin_bit_cast(unsigned, f);
  unsigned r = u + 0x7FFFu + ((u >> 16) & 1u);
  return (unsigned short)(r >> 16);
}

DEV void patch_row(int n, int sc, int lw, int& pt, int& sp0) {
  pt = n >> (2 + 2 * sc);
  int rem = n & ((4 << (2 * sc)) - 1);
  int oh = rem >> (1 + sc), ow = rem & ((2 << sc) - 1);
  sp0 = (oh << (lw + 8)) + (ow << lw);
}

// ---------------- merged prep: weights + mask scalars + Wo repack + zeroing ----------------
__global__ __launch_bounds__(256) void k_prep(const float* __restrict__ Wq, const float* __restrict__ Wk,
                       const float* __restrict__ Wv, const float* __restrict__ bq,
                       const float* __restrict__ bk, const float* __restrict__ bv,
                       const float* __restrict__ Wmq, const float* __restrict__ bmq,
                       const float* __restrict__ Wmk, const float* __restrict__ bmk,
                       const float* __restrict__ Wo,
                       unsigned short* __restrict__ wqkv, float* __restrict__ bias,
                       float* __restrict__ msc, unsigned short* __restrict__ wo3,
                       float* __restrict__ scoresG, unsigned int* __restrict__ pbuf) {
  int bid = blockIdx.x;
  int t = threadIdx.x;
  if (bid < 768) {
    const float* src = bid < 256 ? (Wq + bid * 256) : (bid < 512 ? (Wk + (bid - 256) * 256)
                                                                 : (Wv + (bid - 512) * 256));
    wqkv[bid * 256 + t] = f2bf(src[t]);
    if (t == 0) bias[bid] = bid < 256 ? bq[bid] : (bid < 512 ? bk[bid - 256] : bv[bid - 512]);
    return;
  }
  if (bid == 768) {
    int sc = t >> 6, lane = t & 63;
    int ch = sc * 64 + lane;
    float a0 = Wmq[ch] * Wmk[ch];
    float a1 = Wmq[ch] * bmk[ch];
    float a2 = bmq[ch] * Wmk[ch];
    float a3 = bmq[ch] * bmk[ch];
    for (int off = 32; off; off >>= 1) {
      a0 += __shfl_xor(a0, off); a1 += __shfl_xor(a1, off);
      a2 += __shfl_xor(a2, off); a3 += __shfl_xor(a3, off);
    }
    if (lane == 0) {
      msc[sc * 4 + 0] = a0; msc[sc * 4 + 1] = a1;
      msc[sc * 4 + 2] = a2; msc[sc * 4 + 3] = a3;
    }
    return;
  }
  int blk = bid - 769;
  if (blk < 2304) {
    int didx = blk >> 8, o = blk & 255, c = t;
    wo3[o * 2304 + didx * 256 + c] = f2bf(Wo[o * 2304 + c * 9 + didx]);
  } else {
    int i = (blk - 2304) * 256 + t;
    if (i < 559232) scoresG[i] = 0.f;
    if (i < 140032) pbuf[i] = 0u;
  }
}

// ---------------- mask kernel: gram (bid<328) + rowsum (bid>=328); AFTER k_prep zeroing ----------------
__global__ __launch_bounds__(256) void k_mask(const float* __restrict__ m,
                                              float* __restrict__ G,
                                              float* __restrict__ rbuf) {
  int bid = blockIdx.x;
  int tid = threadIdx.x;
  if (bid >= 328) {
    int row = (bid - 328) * 4 + (tid >> 6);
    int lane = tid & 63;
    if (row < 680) {
      int sc, n;
      if (row < 8)        { sc = 0; n = row; }
      else if (row < 40)  { sc = 1; n = row - 8; }
      else if (row < 168) { sc = 2; n = row - 40; }
      else                { sc = 3; n = row - 168; }
      int lw = 7 - sc, W = 1 << lw;
      int pt, sp0;
      patch_row(n, sc, lw, pt, sp0);
      int base = pt * 65536 + sp0;
      int S = 1 << (14 - 2 * sc);
      float acc = 0.f;
      for (int s = lane; s < S; s += 64) {
        int hh = s >> lw, ww = s & (W - 1);
        acc += m[base + (hh << 8) + ww];
      }
      for (int off = 32; off; off >>= 1) acc += __shfl_xor(acc, off);
      if (lane == 0) rbuf[row] = acc;
    }
    return;
  }
  __shared__ __align__(16) float Ns[32][68];
  __shared__ __align__(16) float Ms[32][68];
  int sc, tn, tm, z, nchunks, soff;
  if (bid < 32)      { sc = 0; tn = 0; tm = 0; z = bid;      nchunks = 8; soff = 0; }
  else if (bid < 40) { sc = 1; tn = 0; tm = 0; z = bid - 32; nchunks = 8; soff = 64; }
  else if (bid < 72) { int r = bid - 40; int tl = r >> 1; sc = 2; tn = tl >> 2; tm = tl & 3; z = r & 1; nchunks = 8; soff = 1088; }
  else               { int tl = bid - 72; sc = 3; tn = tl >> 4; tm = tl & 15; z = 0; nchunks = 4; soff = 17472; }
  int lw = 7 - sc, W = 1 << lw, N = 8 << (2 * sc);
  int kbase = z * nchunks * 64;
  int n0 = tn * 32, m0 = tm * 32;
  bool isA = tid < 128;
  int u = tid & 127;
  int srow = u >> 2, sslot0 = (u & 3) * 4;
  int grow = (isA ? n0 : m0) + srow;
  bool valid = grow < N;
  int pt = 0, sp0 = 0;
  if (valid) patch_row(grow, sc, lw, pt, sp0);
  int gbase = pt * 65536 + sp0;
  int trc = tid >> 4, tcc = tid & 15;
  float a00 = 0.f, a01 = 0.f, a10 = 0.f, a11 = 0.f;
  floatx4 zf = {0.f, 0.f, 0.f, 0.f};
  for (int c = 0; c < nchunks; ++c) {
    int k0 = kbase + c * 64;
    floatx4 v[4];
#pragma unroll
    for (int j = 0; j < 4; ++j) {
      v[j] = zf;
      if (valid) {
        int s = k0 + (sslot0 + j) * 4;
        int hh = s >> lw, ww = s & (W - 1);
        v[j] = *(const floatx4*)(m + gbase + (hh << 8) + ww);
      }
    }
    __syncthreads();
    float* dstrow = isA ? &Ns[srow][0] : &Ms[srow][0];
#pragma unroll
    for (int j = 0; j < 4; ++j) *(floatx4*)&dstrow[(sslot0 + j) * 4] = v[j];
    __syncthreads();
#pragma unroll 4
    for (int k = 0; k < 64; k += 4) {
      floatx4 na = *(const floatx4*)&Ns[2 * trc][k];
      floatx4 nb = *(const floatx4*)&Ns[2 * trc + 1][k];
      floatx4 ma = *(const floatx4*)&Ms[2 * tcc][k];
      floatx4 mb2 = *(const floatx4*)&Ms[2 * tcc + 1][k];
#pragma unroll
      for (int e = 0; e < 4; ++e) {
        a00 += na[e] * ma[e]; a01 += na[e] * mb2[e];
        a10 += nb[e] * ma[e]; a11 += nb[e] * mb2[e];
      }
    }
  }
  int rn = n0 + 2 * trc, rm = m0 + 2 * tcc;
  float res[2][2] = {{a00, a01}, {a10, a11}};
#pragma unroll
  for (int i = 0; i < 2; ++i)
#pragma unroll
    for (int j = 0; j < 2; ++j) {
      if (rn + i < N && rm + j < N) {
        float* dst = &G[soff + (rn + i) * N + rm + j];
        if (sc < 3) atomicAdd(dst, res[i][j]); else *dst = res[i][j];
      }
    }
}

// ---------------- transpose kernels ----------------
__global__ __launch_bounds__(256) void k_xt(const float* __restrict__ x,
                                            unsigned short* __restrict__ xt) {
  __shared__ __align__(16) unsigned short tile[64][72];
  int p0 = blockIdx.x * 64, c0 = blockIdx.y * 64, t = blockIdx.z;
  int tid = threadIdx.x;
  {
    int cc = tid >> 2, pq = (tid & 3) * 16;
    const float* src = x + ((t * 256 + c0 + cc) * 65536 + p0 + pq);
    __align__(16) unsigned short tmp[16];
#pragma unroll
    for (int e = 0; e < 16; e += 4) {
      floatx4 v = *(const floatx4*)(src + e);
      tmp[e + 0] = f2bf(v[0]); tmp[e + 1] = f2bf(v[1]);
      tmp[e + 2] = f2bf(v[2]); tmp[e + 3] = f2bf(v[3]);
    }
    *(uintx4*)&tile[cc][pq] = *(const uintx4*)&tmp[0];
    *(uintx4*)&tile[cc][pq + 8] = *(const uintx4*)&tmp[8];
  }
  __syncthreads();
  {
    int pp = tid >> 2, cg = (tid & 3) * 16;
    __align__(16) unsigned short outv[16];
#pragma unroll
    for (int e = 0; e < 16; ++e) outv[e] = tile[cg + e][pp];
    unsigned short* dst = xt + ((t * 65536 + p0 + pp) * 256 + c0 + cg);
    *(uintx4*)dst = *(const uintx4*)&outv[0];
    *(uintx4*)(dst + 8) = *(const uintx4*)&outv[8];
  }
}

__global__ __launch_bounds__(256) void k_yt(const unsigned short* __restrict__ ynat,
                                            unsigned short* __restrict__ yt) {
  __shared__ __align__(16) unsigned short tile[64][72];
  int p0 = blockIdx.x * 64, c0 = blockIdx.y * 64, t = blockIdx.z;
  int tid = threadIdx.x;
  {
    int cc = tid >> 2, pq = (tid & 3) * 16;
    const unsigned short* src = ynat + ((t * 256 + c0 + cc) * 65536 + p0 + pq);
    *(uintx4*)&tile[cc][pq] = *(const uintx4*)src;
    *(uintx4*)&tile[cc][pq + 8] = *(const uintx4*)(src + 8);
  }
  __syncthreads();
  {
    int pp = tid >> 2, cg = (tid & 3) * 16;
    __align__(16) unsigned short outv[16];
#pragma unroll
    for (int e = 0; e < 16; ++e) outv[e] = tile[cg + e][pp];
    unsigned short* dst = yt + ((t * 65536 + p0 + pp) * 256 + c0 + cg);
    *(uintx4*)dst = *(const uintx4*)&outv[0];
    *(uintx4*)(dst + 8) = *(const uintx4*)&outv[8];
  }
}

// ---------------- QKV GEMM: 128x256 tile + LDS-transposed coalesced epilogue ----------------
__global__ __launch_bounds__(256, 2) void k_qkv(const unsigned short* __restrict__ xt,
                                                const unsigned short* __restrict__ wqkv,
                                                const float* __restrict__ bias,
                                                unsigned short* __restrict__ qkv) {
  extern __shared__ __align__(16) char smem[];
  auto As = (unsigned short (*)[64])(smem);            // [128][64]  16KB
  auto Bs = (unsigned short (*)[64])(smem + 16384);    // [256][64]  32KB
  auto Cs = (unsigned short (*)[280])(smem);           // [64][280]  35KB (overlay)
  int flat = blockIdx.x;
  int lg = (flat & 7) * 384 + (flat >> 3);
  int n_t = lg / 6, m_t = lg - n_t * 6;
  int n0 = n_t << 8, m0 = m_t << 7;
  int tid = threadIdx.x;
  int w = tid >> 6, l = tid & 63;
  int wr = w >> 1, wc = w & 1;
  int l15 = l & 15, lhi = l >> 4;
  int sr = tid >> 1, sbase = (tid & 1) * 4, r7 = sr & 7;
  int b7 = tid & 7;
  const unsigned short* gA = wqkv + (m0 + sr) * 256 + sbase * 8;
  const unsigned short* gB = xt + (n0 + tid) * 256;
  floatx4 zf = {0.f, 0.f, 0.f, 0.f};
  floatx4 acc[4][8];
#pragma unroll
  for (int i = 0; i < 4; ++i)
#pragma unroll
    for (int j = 0; j < 8; ++j) acc[i][j] = zf;
  uintx4 ra[4], rb[8];
#define QLOAD(K0) { const uintx4* pa = (const uintx4*)(gA + (K0)); \
                    ra[0] = pa[0]; ra[1] = pa[1]; ra[2] = pa[2]; ra[3] = pa[3]; \
                    const uintx4* pb = (const uintx4*)(gB + (K0)); \
                    rb[0] = pb[0]; rb[1] = pb[1]; rb[2] = pb[2]; rb[3] = pb[3]; \
                    rb[4] = pb[4]; rb[5] = pb[5]; rb[6] = pb[6]; rb[7] = pb[7]; }
  QLOAD(0);
#pragma unroll
  for (int ch = 0; ch < 4; ++ch) {
    __syncthreads();
#pragma unroll
    for (int j = 0; j < 4; ++j)
      *(uintx4*)&As[sr][((sbase + j) ^ r7) * 8] = ra[j];
#pragma unroll
    for (int j = 0; j < 8; ++j)
      *(uintx4*)&Bs[tid][(j ^ b7) * 8] = rb[j];
    __syncthreads();
    if (ch < 3) QLOAD((ch + 1) * 64);
#pragma unroll
    for (int kk = 0; kk < 2; ++kk) {
      short8 af[4];
#pragma unroll
      for (int f = 0; f < 4; ++f) {
        int arow = wr * 64 + f * 16 + l15;
        af[f] = *(const short8*)&As[arow][(((kk << 2) + lhi) ^ (arow & 7)) * 8];
      }
#pragma unroll
      for (int fn = 0; fn < 8; ++fn) {
        int brow = wc * 128 + fn * 16 + l15;
        short8 b = *(const short8*)&Bs[brow][(((kk << 2) + lhi) ^ (brow & 7)) * 8];
#pragma unroll
        for (int fm = 0; fm < 4; ++fm)
          acc[fm][fn] = __builtin_amdgcn_mfma_f32_16x16x32_bf16(af[fm], b, acc[fm][fn], 0, 0, 0);
      }
    }
  }
#undef QLOAD
#pragma unroll
  for (int h = 0; h < 2; ++h) {
    __syncthreads();
    if (wr == h) {
#pragma unroll
      for (int fm = 0; fm < 4; ++fm) {
#pragma unroll
        for (int rr = 0; rr < 4; ++rr) {
          int rl = fm * 16 + lhi * 4 + rr;
          float bv = bias[m0 + h * 64 + rl];
#pragma unroll
          for (int fn = 0; fn < 8; ++fn)
            Cs[rl][wc * 128 + fn * 16 + l15] = f2bf(acc[fm][fn][rr] + bv);
        }
      }
    }
    __syncthreads();
    {
      int p8 = (tid & 31) * 8;
      int pcol = n0 + p8;
      int t = pcol >> 16, p = pcol & 65535;
#pragma unroll
      for (int pass = 0; pass < 8; ++pass) {
        int rl = (tid >> 5) + pass * 8;
        uintx4 v = *(const uintx4*)&Cs[rl][p8];
        *(uintx4*)&qkv[((t * 768 + m0 + h * 64 + rl) << 16) + p] = v;
      }
    }
  }
}

// ---------------- merged scores: bid<320 big (sc2/sc3, z-split 1024), else 32x32 ----------------
__global__ __launch_bounds__(256) void k_scores_all(const unsigned short* __restrict__ qkv,
                                                    float* __restrict__ scores) {
  __shared__ __align__(16) char sbuf[32768];
  int bid = blockIdx.x;
  int tid = threadIdx.x;
  int w = tid >> 6, l = tid & 63;
  int wr = w >> 1, wc = w & 1, l15 = l & 15, lhi = l >> 4;
  uintx4 zu = {0u, 0u, 0u, 0u};
  floatx4 zf = {0.f, 0.f, 0.f, 0.f};
  if (bid < 320) {
    auto As = (unsigned short (*)[64])(sbuf);
    auto Bs = (unsigned short (*)[64])(sbuf + 16384);
    int lg = (bid & 7) * 40 + (bid >> 3);
    int sc, tn, tm, z, soff;
    if (lg < 64) { sc = 2; tn = 0; tm = 0; z = lg; soff = 1088; }
    else { int r = lg - 64; int tl = r >> 4; sc = 3; tn = tl >> 2; tm = tl & 3; z = r & 15; soff = 17472; }
    int N = 8 << (2 * sc);
    int lw = 7 - sc, W = 1 << lw, lS = 14 - 2 * sc;
    int n0 = tn * 128, m0 = tm * 128;
    int kbase = z * 1024;
    int sr = tid >> 1, sbase = (tid & 1) * 4, r7 = sr & 7;
    int ptA, spA, ptB, spB;
    patch_row(n0 + sr, sc, lw, ptA, spA);
    patch_row(m0 + sr, sc, lw, ptB, spB);
    int baseA = (ptA * 768 + sc * 64) * 65536 + spA;
    int baseB = (ptB * 768 + 256 + sc * 64) * 65536 + spB;
    floatx4 acc[4][4];
#pragma unroll
    for (int i = 0; i < 4; ++i)
#pragma unroll
      for (int j = 0; j < 4; ++j) acc[i][j] = zf;
    uintx4 ra[4], rb[4];
#define GLOAD(K0) { \
  _Pragma("unroll") for (int j = 0; j < 4; ++j) { \
    int k = kbase + (K0) + (sbase + j) * 8; \
    int cl = k >> lS; int s = k & ((1 << lS) - 1); \
    int hh = s >> lw, ww = s & (W - 1); \
    int off = cl * 65536 + (hh << 8) + ww; \
    ra[j] = *(const uintx4*)(qkv + baseA + off); \
    rb[j] = *(const uintx4*)(qkv + baseB + off); } }
    GLOAD(0);
    for (int st = 0; st < 16; ++st) {
      __syncthreads();
#pragma unroll
      for (int j = 0; j < 4; ++j) {
        *(uintx4*)&As[sr][((sbase + j) ^ r7) * 8] = ra[j];
        *(uintx4*)&Bs[sr][((sbase + j) ^ r7) * 8] = rb[j];
      }
      __syncthreads();
      if (st < 15) GLOAD((st + 1) * 64);
#pragma unroll
      for (int kk = 0; kk < 2; ++kk) {
        short8 af[4], bfr[4];
#pragma unroll
        for (int f = 0; f < 4; ++f) {
          int arow = wr * 64 + f * 16 + l15;
          af[f] = *(const short8*)&As[arow][(((kk << 2) + lhi) ^ (arow & 7)) * 8];
          int brow = wc * 64 + f * 16 + l15;
          bfr[f] = *(const short8*)&Bs[brow][(((kk << 2) + lhi) ^ (brow & 7)) * 8];
        }
#pragma unroll
        for (int fm = 0; fm < 4; ++fm)
#pragma unroll
          for (int fn = 0; fn < 4; ++fn)
            acc[fm][fn] = __builtin_amdgcn_mfma_f32_16x16x32_bf16(af[fm], bfr[fn], acc[fm][fn], 0, 0, 0);
      }
    }
#undef GLOAD
#pragma unroll
    for (int fm = 0; fm < 4; ++fm) {
      int nrow = n0 + wr * 64 + fm * 16 + lhi * 4;
#pragma unroll
      for (int rr = 0; rr < 4; ++rr) {
#pragma unroll
        for (int fn = 0; fn < 4; ++fn) {
          int mcol = m0 + wc * 64 + fn * 16 + l15;
          atomicAdd(&scores[soff + (nrow + rr) * N + mcol], acc[fm][fn][rr]);
        }
      }
    }
    return;
  }
  // ---- sc0/sc1 path ----
  {
    auto As = (unsigned short (*)[136])(sbuf);
    auto Bs = (unsigned short (*)[136])(sbuf + 8704);
    int b2 = bid - 320;
    int sc, z, soff;
    if (b2 < 256) { sc = 0; z = b2;       soff = 0; }
    else          { sc = 1; z = b2 - 256; soff = 64; }
    int lw = 7 - sc, W = 1 << lw, lS = 14 - 2 * sc, N = 8 << (2 * sc);
    int kbase = z * 4096;
    floatx4 acc = zf;
    bool isA = tid < 128;
    int u = tid & 127;
    int srow = u >> 2, sslot0 = (u & 3) * 4;
    int grow = srow;
    int cb = (isA ? 0 : 256) + sc * 64;
    int pt = 0, sp0 = 0;
    bool valid = grow < N;
    if (valid) patch_row(grow, sc, lw, pt, sp0);
    int rowbase = (pt * 768 + cb) * 65536 + sp0;
    uintx4 r[4];
#define SLOAD(KS) { int kb2 = kbase + (KS) * 128; \
  _Pragma("unroll") for (int j = 0; j < 4; ++j) { \
    uintx4 v = zu; \
    if (valid) { int k = kb2 + (sslot0 + j) * 8; \
      int cl = k >> lS; int s = k & ((1 << lS) - 1); \
      int hh = s >> lw, ww = s & (W - 1); \
      v = *(const uintx4*)(qkv + rowbase + cl * 65536 + (hh << 8) + ww); } \
    r[j] = v; } }
    SLOAD(0);
    for (int ks = 0; ks < 32; ++ks) {
      __syncthreads();
      {
        unsigned short* dstrow = isA ? &As[srow][0] : &Bs[srow][0];
#pragma unroll
        for (int j = 0; j < 4; ++j) *(uintx4*)&dstrow[(sslot0 + j) * 8] = r[j];
      }
      __syncthreads();
      if (ks < 31) SLOAD(ks + 1);
#pragma unroll
      for (int kk = 0; kk < 4; ++kk) {
        short8 a = *(const short8*)&As[wr * 16 + l15][(kk * 4 + lhi) * 8];
        short8 b = *(const short8*)&Bs[wc * 16 + l15][(kk * 4 + lhi) * 8];
        acc = __builtin_amdgcn_mfma_f32_16x16x32_bf16(a, b, acc, 0, 0, 0);
      }
    }
#undef SLOAD
    int rrow = wr * 16 + lhi * 4;
    int ccol = wc * 16 + l15;
    if (ccol < N) {
#pragma unroll
      for (int rr = 0; rr < 4; ++rr)
        if (rrow + rr < N) atomicAdd(&scores[soff + (rrow + rr) * N + ccol], acc[rr]);
    }
  }
}

// ---------------- logits + softmax -> P bf16 ----------------
__global__ void k_softmax(const float* __restrict__ scores, const float* __restrict__ G,
                          const float* __restrict__ rbuf, const float* __restrict__ msc,
                          unsigned short* __restrict__ pbuf) {
  int row = blockIdx.x, lane = threadIdx.x;
  int sc, n, roff, soff, poff;
  if (row < 8)        { sc = 0; n = row;       roff = 0;   soff = 0;     poff = 0; }
  else if (row < 40)  { sc = 1; n = row - 8;   roff = 8;   soff = 64;    poff = 512; }
  else if (row < 168) { sc = 2; n = row - 40;  roff = 40;  soff = 1088;  poff = 1536; }
  else                { sc = 3; n = row - 168; roff = 168; soff = 17472; poff = 17920; }
  int N = 8 << (2 * sc);
  int Kpad = (sc < 2) ? 32 : N;
  float Sf = (float)(1 << (14 - 2 * sc));
  float invD = 1.0f / (float)(1 << (20 - 2 * sc));
  float alpha = msc[sc * 4 + 0], beta = msc[sc * 4 + 1];
  float gamma = msc[sc * 4 + 2], delta = msc[sc * 4 + 3];
  float rn = rbuf[roff + n];
  float vals[8];
  float mx = -1e30f;
#pragma unroll
  for (int j = 0; j < 8; ++j) {
    float v = -1e30f;
    int mcol = lane + j * 64;
    if (j * 64 < N && mcol < N) {
      float sq = scores[soff + n * N + mcol];
      float g = G[soff + n * N + mcol];
      float rm = rbuf[roff + mcol];
      v = sq * (alpha * g + beta * rn + gamma * rm + delta * Sf) * invD;
    }
    vals[j] = v;
    mx = fmaxf(mx, v);
  }
  for (int off = 32; off; off >>= 1) mx = fmaxf(mx, __shfl_xor(mx, off));
  float sum = 0.f;
#pragma unroll
  for (int j = 0; j < 8; ++j) {
    int mcol = lane + j * 64;
    float e = 0.f;
    if (j * 64 < N && mcol < N) e = __expf(vals[j] - mx);
    vals[j] = e;
    sum += e;
  }
  for (int off = 32; off; off >>= 1) sum += __shfl_xor(sum, off);
  float inv = 1.f / sum;
#pragma unroll
  for (int j = 0; j < 8; ++j) {
    int mcol = lane + j * 64;
    if (j * 64 < N && mcol < N) pbuf[poff + n * Kpad + mcol] = f2bf(vals[j] * inv);
  }
}

// ---------------- PV GEMM: dbuf LDS, 1 barrier/K-step, balanced XCD co-location ----------------
__global__ __launch_bounds__(256) void k_pv(const unsigned short* __restrict__ qkv,
                                            const unsigned short* __restrict__ pbuf,
                                            unsigned short* __restrict__ ynat) {
  int bid0 = blockIdx.x;
  int bid;
  if (bid0 < 6144) {
    bid = bid0;
  } else if (bid0 < 8192) {
    int q = bid0 - 6144; int c = q & 7, j = q >> 3;
    bid = 6144 + ((c * 128 + (j & 127)) << 1) + (j >> 7);
  } else {
    int q = bid0 - 8192; int c = q & 7, j = q >> 3;
    bid = 8192 + ((c * 32 + (j & 31)) << 3) + (j >> 5);
  }
  int sc, bx, by;
  if (bid < 4096)      { sc = 0; bx = bid; by = 0; }
  else if (bid < 6144) { sc = 1; bx = bid - 4096; by = 0; }
  else if (bid < 8192) { int r = bid - 6144; sc = 2; bx = r >> 1; by = r & 1; }
  else                 { int r = bid - 8192; sc = 3; bx = r >> 3; by = r & 7; }
  int WR    = (sc == 0) ? 1 : (sc == 1) ? 2 : 4;
  int logWC = (sc == 0) ? 2 : (sc == 1) ? 1 : 0;
  int poff  = (sc == 0) ? 0 : (sc == 1) ? 512 : (sc == 2) ? 1536 : 17920;
  int lw = 7 - sc, W = 1 << lw;
  int lS = 14 - 2 * sc;
  int N = 8 << (2 * sc);
  int Kpad = (sc < 2) ? 32 : N;
  int WC = 1 << logWC;
  int d0 = bx * (WC * 64);
  int nb = by * (WR * 16);
  __shared__ __align__(16) unsigned short As[2][64][40];
  __shared__ __align__(16) unsigned short Bt[2][256][32];
  int tid = threadIdx.x;
  int w = tid >> 6, l = tid & 63;
  int wr = w >> logWC, wc = w & (WC - 1);
  int l15 = l & 15, lhi = l >> 4;
  floatx4 zf = {0.f, 0.f, 0.f, 0.f};
  floatx4 acc[4];
#pragma unroll
  for (int i = 0; i < 4; ++i) acc[i] = zf;
  int bmp = tid & 15;
  int dg = tid >> 4;
  bool act0 = (WC > 1) || (dg < 8);
  bool has1 = (WC == 4);
  bool doA = tid < WR * 64;
  int arow = tid >> 2, akg = (tid & 3) * 8;
  int ksteps = Kpad >> 5;
  uintx4 zu = {0u, 0u, 0u, 0u};
  int vcb = (512 + sc * 64) * 65536;
  uintx4 av = zu, lo0 = zu, hi0 = zu, lo1 = zu, hi1 = zu;
#define PLOADS(KS) { int k0 = (KS) * 32; \
    av = zu; lo0 = zu; hi0 = zu; lo1 = zu; hi1 = zu; \
    if (doA) av = *(const uintx4*)(pbuf + poff + (nb + arow) * Kpad + k0 + akg); \
    int gm0 = k0 + 2 * bmp, gm1 = gm0 + 1; \
    bool mv0 = gm0 < N, mv1 = gm1 < N; \
    int pt0 = 0, sp00 = 0, pt1 = 0, sp01 = 0; \
    if (mv0) patch_row(gm0, sc, lw, pt0, sp00); \
    if (mv1) patch_row(gm1, sc, lw, pt1, sp01); \
    { int d = d0 + dg * 8; int cl = d >> lS; int s = d & ((1 << lS) - 1); \
      int hh = s >> lw, ww = s & (W - 1); int sp = (hh << 8) + ww; \
      if (act0 && mv0) lo0 = *(const uintx4*)(qkv + pt0 * 768 * 65536 + vcb + cl * 65536 + sp00 + sp); \
      if (act0 && mv1) hi0 = *(const uintx4*)(qkv + pt1 * 768 * 65536 + vcb + cl * 65536 + sp01 + sp); } \
    if (has1) { int d = d0 + (dg + 16) * 8; int cl = d >> lS; int s = d & ((1 << lS) - 1); \
      int hh = s >> lw, ww = s & (W - 1); int sp = (hh << 8) + ww; \
      if (mv0) lo1 = *(const uintx4*)(qkv + pt0 * 768 * 65536 + vcb + cl * 65536 + sp00 + sp); \
      if (mv1) hi1 = *(const uintx4*)(qkv + pt1 * 768 * 65536 + vcb + cl * 65536 + sp01 + sp); } }
  PLOADS(0);
  for (int ks = 0; ks < ksteps; ++ks) {
    int b = ks & 1;
    if (doA) *(uintx4*)&As[b][arow][akg] = av;
    if (act0) {
      int du = dg * 8;
#pragma unroll
      for (int j = 0; j < 8; ++j) {
        int d = du + j;
        unsigned losh = (lo0[j >> 1] >> ((j & 1) * 16)) & 0xFFFFu;
        unsigned hish = (hi0[j >> 1] >> ((j & 1) * 16)) & 0xFFFFu;
        unsigned wv = losh | (hish << 16);
        int slot = (bmp >> 2) ^ ((d >> 1) & 3) ^ ((d >> 3) & 3);
        ((unsigned int*)&Bt[b][d][0])[slot * 4 + (bmp & 3)] = wv;
      }
    }
    if (has1) {
      int du = (dg + 16) * 8;
#pragma unroll
      for (int j = 0; j < 8; ++j) {
        int d = du + j;
        unsigned losh = (lo1[j >> 1] >> ((j & 1) * 16)) & 0xFFFFu;
        unsigned hish = (hi1[j >> 1] >> ((j & 1) * 16)) & 0xFFFFu;
        unsigned wv = losh | (hish << 16);
        int slot = (bmp >> 2) ^ ((d >> 1) & 3) ^ ((d >> 3) & 3);
        ((unsigned int*)&Bt[b][d][0])[slot * 4 + (bmp & 3)] = wv;
      }
    }
    __syncthreads();
    if (ks + 1 < ksteps) PLOADS(ks + 1);
    short8 a = *(const short8*)&As[b][wr * 16 + l15][lhi * 8];
#pragma unroll
    for (int fn = 0; fn < 4; ++fn) {
      int row = wc * 64 + fn * 16 + l15;
      int slot = lhi ^ ((row >> 1) & 3) ^ ((row >> 3) & 3);
      short8 bb = *(const short8*)&Bt[b][row][slot * 8];
      acc[fn] = __builtin_amdgcn_mfma_f32_16x16x32_bf16(a, bb, acc[fn], 0, 0, 0);
    }
  }
#undef PLOADS
  int nrow = nb + wr * 16 + lhi * 4;
#pragma unroll
  for (int rr = 0; rr < 4; ++rr) {
    int n = nrow + rr;
    if (n < N) {
      int pt, sp0;
      patch_row(n, sc, lw, pt, sp0);
#pragma unroll
      for (int fn = 0; fn < 4; ++fn) {
        int d = d0 + wc * 64 + fn * 16 + l15;
        int cl = d >> lS;
        int s = d & ((1 << lS) - 1);
        int hh = s >> lw, ww = s & (W - 1);
        int c = sc * 64 + cl;
        ynat[(pt * 256 + c) * 65536 + sp0 + (hh << 8) + ww] = f2bf(acc[fn][rr]);
      }
    }
  }
}

// ---------------- conv3x3: 256x256 8-wave reg-staged GEMM, BK=64 tap-major ----------------
__global__ __launch_bounds__(512, 1) void k_conv(const unsigned short* __restrict__ yt,
                                                 const unsigned short* __restrict__ wo3,
                                                 const float* __restrict__ bo,
                                                 float* __restrict__ out) {
  __shared__ __align__(16) unsigned short Asm[2][256][64];
  __shared__ __align__(16) unsigned short Bsm[2][256][64];
  int flat = blockIdx.x;                      // 512 blocks
  int lg = (flat & 7) * 64 + (flat >> 3);     // bijective XCD chunking (8x64)
  int tt = lg >> 8, yy = lg & 255;            // n-tile = one image row
  int tid = threadIdx.x;
  int w = tid >> 6, l = tid & 63;
  int wr = w >> 2, wc = w & 3;                // 2 x 4 waves
  int l15 = l & 15, lhi = l >> 4;
  int sr = tid >> 1, sbase = (tid & 1) * 4, r7 = sr & 7;
  const unsigned short* gA = wo3 + sr * 2304 + sbase * 8;
  const unsigned short* ybase = yt + (tt << 24);
  floatx4 zf = {0.f, 0.f, 0.f, 0.f};
  floatx4 acc[8][4];
#pragma unroll
  for (int i = 0; i < 8; ++i)
#pragma unroll
    for (int j = 0; j < 4; ++j) acc[i][j] = zf;
  uintx4 zu = {0u, 0u, 0u, 0u};
  uintx4 ra[4], rb[4];
#define CLOAD(ST) { \
    const uintx4* pa = (const uintx4*)(gA + (ST) * 64); \
    ra[0] = pa[0]; ra[1] = pa[1]; ra[2] = pa[2]; ra[3] = pa[3]; \
    int tap = (ST) >> 2, ch0 = ((ST) & 3) << 6; \
    int dy3 = (tap * 11) >> 5; int dy = dy3 - 1; int dx = tap - dy3 * 3 - 1; \
    int yq = yy + dy, xq = sr + dx; \
    if (((unsigned)yq < 256u) && ((unsigned)xq < 256u)) { \
      const uintx4* pb = (const uintx4*)(ybase + ((yq << 8) + xq) * 256 + ch0 + sbase * 8); \
      rb[0] = pb[0]; rb[1] = pb[1]; rb[2] = pb[2]; rb[3] = pb[3]; \
    } else { rb[0] = zu; rb[1] = zu; rb[2] = zu; rb[3] = zu; } }
  CLOAD(0);
  for (int st = 0; st < 36; ++st) {
    int cur = st & 1;
    __syncthreads();
#pragma unroll
    for (int j = 0; j < 4; ++j) {
      *(uintx4*)&Asm[cur][sr][((sbase + j) ^ r7) * 8] = ra[j];
      *(uintx4*)&Bsm[cur][sr][((sbase + j) ^ r7) * 8] = rb[j];
    }
    __syncthreads();
    if (st < 35) CLOAD(st + 1);
#pragma unroll
    for (int kk = 0; kk < 2; ++kk) {
      short8 bf[4];
#pragma unroll
      for (int fn = 0; fn < 4; ++fn) {
        int brow = wc * 64 + fn * 16 + l15;
        bf[fn] = *(const short8*)&Bsm[cur][brow][(((kk << 2) + lhi) ^ (brow & 7)) * 8];
      }
#pragma unroll
      for (int fm = 0; fm < 8; ++fm) {
        int arow = wr * 128 + fm * 16 + l15;
        short8 af = *(const short8*)&Asm[cur][arow][(((kk << 2) + lhi) ^ (arow & 7)) * 8];
#pragma unroll
        for (int fn = 0; fn < 4; ++fn)
          acc[fm][fn] = __builtin_amdgcn_mfma_f32_16x16x32_bf16(af, bf[fn], acc[fm][fn], 0, 0, 0);
      }
    }
  }
#undef CLOAD
#pragma unroll
  for (int fm = 0; fm < 8; ++fm) {
    int o = wr * 128 + fm * 16 + lhi * 4;
#pragma unroll
    for (int rr = 0; rr < 4; ++rr) {
      float bias = bo[o + rr];
#pragma unroll
      for (int fn = 0; fn < 4; ++fn) {
        int xcol = wc * 64 + fn * 16 + l15;
        float z = acc[fm][fn][rr] + bias;
        out[((tt * 256 + o + rr) << 16) + (yy << 8) + xcol] = z > 0.f ? z : 0.2f * z;
      }
    }
  }
}

// ---------------------------------------------------------------------------
extern "C" void kernel_launch(void* const* d_in, const int* in_sizes, int n_in,
                              void* d_out, int out_size, void* d_ws, size_t ws_size,
                              hipStream_t stream) {
  const float* x   = (const float*)d_in[0];
  const float* m   = (const float*)d_in[1];
  const float* Wq  = (const float*)d_in[2];
  const float* bq  = (const float*)d_in[3];
  const float* Wk  = (const float*)d_in[4];
  const float* bk  = (const float*)d_in[5];
  const float* Wv  = (const float*)d_in[6];
  const float* bv  = (const float*)d_in[7];
  const float* Wmq = (const float*)d_in[8];
  const float* bmq = (const float*)d_in[9];
  const float* Wmk = (const float*)d_in[10];
  const float* bmk = (const float*)d_in[11];
  const float* Wo  = (const float*)d_in[12];
  const float* bo  = (const float*)d_in[13];

  char* ws = (char*)d_ws;
  unsigned short* qkv   = (unsigned short*)(ws);
  unsigned short* xtb   = (unsigned short*)(ws + 201326592);  // xt, later yt
  unsigned short* wqkv  = (unsigned short*)(ws + 268435456);
  unsigned short* wo3   = (unsigned short*)(ws + 268828672);
  float* bias           = (float*)(ws + 270008320);
  float* msc            = (float*)(ws + 270011392);
  float* scores         = (float*)(ws + 270011456);
  float* G              = (float*)(ws + 271129920);
  float* rbuf           = (float*)(ws + 272248384);
  unsigned short* pbuf  = (unsigned short*)(ws + 272251104);
  float* out            = (float*)d_out;
  unsigned short* ynat  = (unsigned short*)d_out;  // low half of d_out as bf16 scratch

  k_prep<<<dim3(5258), dim3(256), 0, stream>>>(Wq, Wk, Wv, bq, bk, bv, Wmq, bmq, Wmk, bmk,
                                               Wo, wqkv, bias, msc, wo3, scores,
                                               (unsigned int*)pbuf);
  k_xt<<<dim3(1024, 4, 2), dim3(256), 0, stream>>>(x, xtb);
  k_qkv<<<dim3(3072), dim3(256), 49152, stream>>>(xtb, wqkv, bias, qkv);
  k_mask<<<dim3(498), dim3(256), 0, stream>>>(m, G, rbuf);
  k_scores_all<<<dim3(640), dim3(256), 0, stream>>>(qkv, scores);
  k_softmax<<<dim3(680), dim3(64), 0, stream>>>(scores, G, rbuf, msc, pbuf);
  k_pv<<<dim3(10240), dim3(256), 0, stream>>>(qkv, pbuf, ynat);
  k_yt<<<dim3(1024, 4, 2), dim3(256), 0, stream>>>(ynat, xtb);
  k_conv<<<dim3(512), dim3(512), 0, stream>>>(xtb, wo3, bo, out);
}

// Round 14
// 525.295 us; speedup vs baseline: 1.1027x; 1.1027x over previous
//
#include <hip/hip_runtime.h>
#include <stdint.h>

// ---------------------------------------------------------------------------
// MultiHeadedAttention (4-scale patch attention) for MI355X / gfx950
// R14: conv frozen at R9/R11 halo kernel (5 restructures all landed 211-231
//      vs halo 187-189). Full R11 config + k_mask merged into k_xt launch
//      (safe: zeroing is in the prior k_prep launch). 8 launches.
// ---------------------------------------------------------------------------

typedef __attribute__((ext_vector_type(8))) short short8;
typedef __attribute__((ext_vector_type(4))) float floatx4;
typedef __attribute__((ext_vector_type(4))) unsigned int uintx4;

#define DEV static __device__ __forceinline__

DEV unsigned short f2bf(float f) {
  unsigned u = __builtin_bit_cast(unsigned, f);
  unsigned r = u + 0x7FFFu + ((u >> 16) & 1u);
  return (unsigned short)(r >> 16);
}

DEV void patch_row(int n, int sc, int lw, int& pt, int& sp0) {
  pt = n >> (2 + 2 * sc);
  int rem = n & ((4 << (2 * sc)) - 1);
  int oh = rem >> (1 + sc), ow = rem & ((2 << sc) - 1);
  sp0 = (oh << (lw + 8)) + (ow << lw);
}

// ---------------- merged prep: weights + mask scalars + Wo repack + zeroing ----------------
__global__ __launch_bounds__(256) void k_prep(const float* __restrict__ Wq, const float* __restrict__ Wk,
                       const float* __restrict__ Wv, const float* __restrict__ bq,
                       const float* __restrict__ bk, const float* __restrict__ bv,
                       const float* __restrict__ Wmq, const float* __restrict__ bmq,
                       const float* __restrict__ Wmk, const float* __restrict__ bmk,
                       const float* __restrict__ Wo,
                       unsigned short* __restrict__ wqkv, float* __restrict__ bias,
                       float* __restrict__ msc, unsigned short* __restrict__ wobf,
                       float* __restrict__ scoresG, unsigned int* __restrict__ pbuf) {
  int bid = blockIdx.x;
  int t = threadIdx.x;
  if (bid < 768) {
    const float* src = bid < 256 ? (Wq + bid * 256) : (bid < 512 ? (Wk + (bid - 256) * 256)
                                                                 : (Wv + (bid - 512) * 256));
    wqkv[bid * 256 + t] = f2bf(src[t]);
    if (t == 0) bias[bid] = bid < 256 ? bq[bid] : (bid < 512 ? bk[bid - 256] : bv[bid - 512]);
    return;
  }
  if (bid == 768) {
    int sc = t >> 6, lane = t & 63;
    int ch = sc * 64 + lane;
    float a0 = Wmq[ch] * Wmk[ch];
    float a1 = Wmq[ch] * bmk[ch];
    float a2 = bmq[ch] * Wmk[ch];
    float a3 = bmq[ch] * bmk[ch];
    for (int off = 32; off; off >>= 1) {
      a0 += __shfl_xor(a0, off); a1 += __shfl_xor(a1, off);
      a2 += __shfl_xor(a2, off); a3 += __shfl_xor(a3, off);
    }
    if (lane == 0) {
      msc[sc * 4 + 0] = a0; msc[sc * 4 + 1] = a1;
      msc[sc * 4 + 2] = a2; msc[sc * 4 + 3] = a3;
    }
    return;
  }
  int blk = bid - 769;
  if (blk < 2304) {
    int didx = blk >> 8, o = blk & 255, c = t;
    wobf[didx * 65536 + o * 256 + c] = f2bf(Wo[o * 2304 + c * 9 + didx]);
  } else {
    int i = (blk - 2304) * 256 + t;
    if (i < 559232) scoresG[i] = 0.f;
    if (i < 140032) pbuf[i] = 0u;
  }
}

// ---------------- x transpose (bid<8192) + mask gram/rowsum (bid>=8192) ----------------
__global__ __launch_bounds__(256) void k_xtm(const float* __restrict__ x,
                                             unsigned short* __restrict__ xt,
                                             const float* __restrict__ m,
                                             float* __restrict__ G,
                                             float* __restrict__ rbuf) {
  int bid = blockIdx.x;
  int tid = threadIdx.x;
  if (bid < 8192) {
    __shared__ __align__(16) unsigned short tile[64][72];
    int p0 = (bid & 1023) * 64, c0 = ((bid >> 10) & 3) * 64, t = bid >> 12;
    {
      int cc = tid >> 2, pq = (tid & 3) * 16;
      const float* src = x + ((t * 256 + c0 + cc) * 65536 + p0 + pq);
      __align__(16) unsigned short tmp[16];
#pragma unroll
      for (int e = 0; e < 16; e += 4) {
        floatx4 v = *(const floatx4*)(src + e);
        tmp[e + 0] = f2bf(v[0]); tmp[e + 1] = f2bf(v[1]);
        tmp[e + 2] = f2bf(v[2]); tmp[e + 3] = f2bf(v[3]);
      }
      *(uintx4*)&tile[cc][pq] = *(const uintx4*)&tmp[0];
      *(uintx4*)&tile[cc][pq + 8] = *(const uintx4*)&tmp[8];
    }
    __syncthreads();
    {
      int pp = tid >> 2, cg = (tid & 3) * 16;
      __align__(16) unsigned short outv[16];
#pragma unroll
      for (int e = 0; e < 16; ++e) outv[e] = tile[cg + e][pp];
      unsigned short* dst = xt + ((t * 65536 + p0 + pp) * 256 + c0 + cg);
      *(uintx4*)dst = *(const uintx4*)&outv[0];
      *(uintx4*)(dst + 8) = *(const uintx4*)&outv[8];
    }
    return;
  }
  int mb = bid - 8192;
  if (mb >= 328) {
    int row = (mb - 328) * 4 + (tid >> 6);
    int lane = tid & 63;
    if (row < 680) {
      int sc, n;
      if (row < 8)        { sc = 0; n = row; }
      else if (row < 40)  { sc = 1; n = row - 8; }
      else if (row < 168) { sc = 2; n = row - 40; }
      else                { sc = 3; n = row - 168; }
      int lw = 7 - sc, W = 1 << lw;
      int pt, sp0;
      patch_row(n, sc, lw, pt, sp0);
      int base = pt * 65536 + sp0;
      int S = 1 << (14 - 2 * sc);
      float acc = 0.f;
      for (int s = lane; s < S; s += 64) {
        int hh = s >> lw, ww = s & (W - 1);
        acc += m[base + (hh << 8) + ww];
      }
      for (int off = 32; off; off >>= 1) acc += __shfl_xor(acc, off);
      if (lane == 0) rbuf[row] = acc;
    }
    return;
  }
  __shared__ __align__(16) float Ns[32][68];
  __shared__ __align__(16) float Ms[32][68];
  int sc, tn, tm, z, nchunks, soff;
  if (mb < 32)      { sc = 0; tn = 0; tm = 0; z = mb;      nchunks = 8; soff = 0; }
  else if (mb < 40) { sc = 1; tn = 0; tm = 0; z = mb - 32; nchunks = 8; soff = 64; }
  else if (mb < 72) { int r = mb - 40; int tl = r >> 1; sc = 2; tn = tl >> 2; tm = tl & 3; z = r & 1; nchunks = 8; soff = 1088; }
  else              { int tl = mb - 72; sc = 3; tn = tl >> 4; tm = tl & 15; z = 0; nchunks = 4; soff = 17472; }
  int lw = 7 - sc, W = 1 << lw, N = 8 << (2 * sc);
  int kbase = z * nchunks * 64;
  int n0 = tn * 32, m0 = tm * 32;
  bool isA = tid < 128;
  int u = tid & 127;
  int srow = u >> 2, sslot0 = (u & 3) * 4;
  int grow = (isA ? n0 : m0) + srow;
  bool valid = grow < N;
  int pt = 0, sp0 = 0;
  if (valid) patch_row(grow, sc, lw, pt, sp0);
  int gbase = pt * 65536 + sp0;
  int trc = tid >> 4, tcc = tid & 15;
  float a00 = 0.f, a01 = 0.f, a10 = 0.f, a11 = 0.f;
  floatx4 zf = {0.f, 0.f, 0.f, 0.f};
  for (int c = 0; c < nchunks; ++c) {
    int k0 = kbase + c * 64;
    floatx4 v[4];
#pragma unroll
    for (int j = 0; j < 4; ++j) {
      v[j] = zf;
      if (valid) {
        int s = k0 + (sslot0 + j) * 4;
        int hh = s >> lw, ww = s & (W - 1);
        v[j] = *(const floatx4*)(m + gbase + (hh << 8) + ww);
      }
    }
    __syncthreads();
    float* dstrow = isA ? &Ns[srow][0] : &Ms[srow][0];
#pragma unroll
    for (int j = 0; j < 4; ++j) *(floatx4*)&dstrow[(sslot0 + j) * 4] = v[j];
    __syncthreads();
#pragma unroll 4
    for (int k = 0; k < 64; k += 4) {
      floatx4 na = *(const floatx4*)&Ns[2 * trc][k];
      floatx4 nb = *(const floatx4*)&Ns[2 * trc + 1][k];
      floatx4 ma = *(const floatx4*)&Ms[2 * tcc][k];
      floatx4 mb2 = *(const floatx4*)&Ms[2 * tcc + 1][k];
#pragma unroll
      for (int e = 0; e < 4; ++e) {
        a00 += na[e] * ma[e]; a01 += na[e] * mb2[e];
        a10 += nb[e] * ma[e]; a11 += nb[e] * mb2[e];
      }
    }
  }
  int rn = n0 + 2 * trc, rm = m0 + 2 * tcc;
  float res[2][2] = {{a00, a01}, {a10, a11}};
#pragma unroll
  for (int i = 0; i < 2; ++i)
#pragma unroll
    for (int j = 0; j < 2; ++j) {
      if (rn + i < N && rm + j < N) {
        float* dst = &G[soff + (rn + i) * N + rm + j];
        if (sc < 3) atomicAdd(dst, res[i][j]); else *dst = res[i][j];
      }
    }
}

// ---------------- y transpose ----------------
__global__ __launch_bounds__(256) void k_yt(const unsigned short* __restrict__ ynat,
                                            unsigned short* __restrict__ yt) {
  __shared__ __align__(16) unsigned short tile[64][72];
  int p0 = blockIdx.x * 64, c0 = blockIdx.y * 64, t = blockIdx.z;
  int tid = threadIdx.x;
  {
    int cc = tid >> 2, pq = (tid & 3) * 16;
    const unsigned short* src = ynat + ((t * 256 + c0 + cc) * 65536 + p0 + pq);
    *(uintx4*)&tile[cc][pq] = *(const uintx4*)src;
    *(uintx4*)&tile[cc][pq + 8] = *(const uintx4*)(src + 8);
  }
  __syncthreads();
  {
    int pp = tid >> 2, cg = (tid & 3) * 16;
    __align__(16) unsigned short outv[16];
#pragma unroll
    for (int e = 0; e < 16; ++e) outv[e] = tile[cg + e][pp];
    unsigned short* dst = yt + ((t * 65536 + p0 + pp) * 256 + c0 + cg);
    *(uintx4*)dst = *(const uintx4*)&outv[0];
    *(uintx4*)(dst + 8) = *(const uintx4*)&outv[8];
  }
}

// ---------------- QKV GEMM: 128x256 tile + LDS-transposed coalesced epilogue ----------------
__global__ __launch_bounds__(256, 2) void k_qkv(const unsigned short* __restrict__ xt,
                                                const unsigned short* __restrict__ wqkv,
                                                const float* __restrict__ bias,
                                                unsigned short* __restrict__ qkv) {
  extern __shared__ __align__(16) char smem[];
  auto As = (unsigned short (*)[64])(smem);            // [128][64]  16KB
  auto Bs = (unsigned short (*)[64])(smem + 16384);    // [256][64]  32KB
  auto Cs = (unsigned short (*)[280])(smem);           // [64][280]  35KB (overlay)
  int flat = blockIdx.x;
  int lg = (flat & 7) * 384 + (flat >> 3);
  int n_t = lg / 6, m_t = lg - n_t * 6;
  int n0 = n_t << 8, m0 = m_t << 7;
  int tid = threadIdx.x;
  int w = tid >> 6, l = tid & 63;
  int wr = w >> 1, wc = w & 1;
  int l15 = l & 15, lhi = l >> 4;
  int sr = tid >> 1, sbase = (tid & 1) * 4, r7 = sr & 7;
  int b7 = tid & 7;
  const unsigned short* gA = wqkv + (m0 + sr) * 256 + sbase * 8;
  const unsigned short* gB = xt + (n0 + tid) * 256;
  floatx4 zf = {0.f, 0.f, 0.f, 0.f};
  floatx4 acc[4][8];
#pragma unroll
  for (int i = 0; i < 4; ++i)
#pragma unroll
    for (int j = 0; j < 8; ++j) acc[i][j] = zf;
  uintx4 ra[4], rb[8];
#define QLOAD(K0) { const uintx4* pa = (const uintx4*)(gA + (K0)); \
                    ra[0] = pa[0]; ra[1] = pa[1]; ra[2] = pa[2]; ra[3] = pa[3]; \
                    const uintx4* pb = (const uintx4*)(gB + (K0)); \
                    rb[0] = pb[0]; rb[1] = pb[1]; rb[2] = pb[2]; rb[3] = pb[3]; \
                    rb[4] = pb[4]; rb[5] = pb[5]; rb[6] = pb[6]; rb[7] = pb[7]; }
  QLOAD(0);
#pragma unroll
  for (int ch = 0; ch < 4; ++ch) {
    __syncthreads();
#pragma unroll
    for (int j = 0; j < 4; ++j)
      *(uintx4*)&As[sr][((sbase + j) ^ r7) * 8] = ra[j];
#pragma unroll
    for (int j = 0; j < 8; ++j)
      *(uintx4*)&Bs[tid][(j ^ b7) * 8] = rb[j];
    __syncthreads();
    if (ch < 3) QLOAD((ch + 1) * 64);
#pragma unroll
    for (int kk = 0; kk < 2; ++kk) {
      short8 af[4];
#pragma unroll
      for (int f = 0; f < 4; ++f) {
        int arow = wr * 64 + f * 16 + l15;
        af[f] = *(const short8*)&As[arow][(((kk << 2) + lhi) ^ (arow & 7)) * 8];
      }
#pragma unroll
      for (int fn = 0; fn < 8; ++fn) {
        int brow = wc * 128 + fn * 16 + l15;
        short8 b = *(const short8*)&Bs[brow][(((kk << 2) + lhi) ^ (brow & 7)) * 8];
#pragma unroll
        for (int fm = 0; fm < 4; ++fm)
          acc[fm][fn] = __builtin_amdgcn_mfma_f32_16x16x32_bf16(af[fm], b, acc[fm][fn], 0, 0, 0);
      }
    }
  }
#undef QLOAD
#pragma unroll
  for (int h = 0; h < 2; ++h) {
    __syncthreads();
    if (wr == h) {
#pragma unroll
      for (int fm = 0; fm < 4; ++fm) {
#pragma unroll
        for (int rr = 0; rr < 4; ++rr) {
          int rl = fm * 16 + lhi * 4 + rr;
          float bv = bias[m0 + h * 64 + rl];
#pragma unroll
          for (int fn = 0; fn < 8; ++fn)
            Cs[rl][wc * 128 + fn * 16 + l15] = f2bf(acc[fm][fn][rr] + bv);
        }
      }
    }
    __syncthreads();
    {
      int p8 = (tid & 31) * 8;
      int pcol = n0 + p8;
      int t = pcol >> 16, p = pcol & 65535;
#pragma unroll
      for (int pass = 0; pass < 8; ++pass) {
        int rl = (tid >> 5) + pass * 8;
        uintx4 v = *(const uintx4*)&Cs[rl][p8];
        *(uintx4*)&qkv[((t * 768 + m0 + h * 64 + rl) << 16) + p] = v;
      }
    }
  }
}

// ---------------- merged scores: bid<160 big (sc2/sc3), else 32x32 (sc0/sc1) ----------------
__global__ __launch_bounds__(256) void k_scores_all(const unsigned short* __restrict__ qkv,
                                                    float* __restrict__ scores) {
  __shared__ __align__(16) char sbuf[32768];
  int bid = blockIdx.x;
  int tid = threadIdx.x;
  int w = tid >> 6, l = tid & 63;
  int wr = w >> 1, wc = w & 1, l15 = l & 15, lhi = l >> 4;
  uintx4 zu = {0u, 0u, 0u, 0u};
  floatx4 zf = {0.f, 0.f, 0.f, 0.f};
  if (bid < 160) {
    auto As = (unsigned short (*)[64])(sbuf);
    auto Bs = (unsigned short (*)[64])(sbuf + 16384);
    int lg = (bid & 7) * 20 + (bid >> 3);
    int sc, tn, tm, z, soff;
    if (lg < 32) { sc = 2; tn = 0; tm = 0; z = lg; soff = 1088; }
    else { int r = lg - 32; int tl = r >> 3; sc = 3; tn = tl >> 2; tm = tl & 3; z = r & 7; soff = 17472; }
    int N = 8 << (2 * sc);
    int lw = 7 - sc, W = 1 << lw, lS = 14 - 2 * sc;
    int n0 = tn * 128, m0 = tm * 128;
    int kbase = z * 2048;
    int sr = tid >> 1, sbase = (tid & 1) * 4, r7 = sr & 7;
    int ptA, spA, ptB, spB;
    patch_row(n0 + sr, sc, lw, ptA, spA);
    patch_row(m0 + sr, sc, lw, ptB, spB);
    int baseA = (ptA * 768 + sc * 64) * 65536 + spA;
    int baseB = (ptB * 768 + 256 + sc * 64) * 65536 + spB;
    floatx4 acc[4][4];
#pragma unroll
    for (int i = 0; i < 4; ++i)
#pragma unroll
      for (int j = 0; j < 4; ++j) acc[i][j] = zf;
    uintx4 ra[4], rb[4];
#define GLOAD(K0) { \
  _Pragma("unroll") for (int j = 0; j < 4; ++j) { \
    int k = kbase + (K0) + (sbase + j) * 8; \
    int cl = k >> lS; int s = k & ((1 << lS) - 1); \
    int hh = s >> lw, ww = s & (W - 1); \
    int off = cl * 65536 + (hh << 8) + ww; \
    ra[j] = *(const uintx4*)(qkv + baseA + off); \
    rb[j] = *(const uintx4*)(qkv + baseB + off); } }
    GLOAD(0);
    for (int st = 0; st < 32; ++st) {
      __syncthreads();
#pragma unroll
      for (int j = 0; j < 4; ++j) {
        *(uintx4*)&As[sr][((sbase + j) ^ r7) * 8] = ra[j];
        *(uintx4*)&Bs[sr][((sbase + j) ^ r7) * 8] = rb[j];
      }
      __syncthreads();
      if (st < 31) GLOAD((st + 1) * 64);
#pragma unroll
      for (int kk = 0; kk < 2; ++kk) {
        short8 af[4], bfr[4];
#pragma unroll
        for (int f = 0; f < 4; ++f) {
          int arow = wr * 64 + f * 16 + l15;
          af[f] = *(const short8*)&As[arow][(((kk << 2) + lhi) ^ (arow & 7)) * 8];
          int brow = wc * 64 + f * 16 + l15;
          bfr[f] = *(const short8*)&Bs[brow][(((kk << 2) + lhi) ^ (brow & 7)) * 8];
        }
#pragma unroll
        for (int fm = 0; fm < 4; ++fm)
#pragma unroll
          for (int fn = 0; fn < 4; ++fn)
            acc[fm][fn] = __builtin_amdgcn_mfma_f32_16x16x32_bf16(af[fm], bfr[fn], acc[fm][fn], 0, 0, 0);
      }
    }
#undef GLOAD
#pragma unroll
    for (int fm = 0; fm < 4; ++fm) {
      int nrow = n0 + wr * 64 + fm * 16 + lhi * 4;
#pragma unroll
      for (int rr = 0; rr < 4; ++rr) {
#pragma unroll
        for (int fn = 0; fn < 4; ++fn) {
          int mcol = m0 + wc * 64 + fn * 16 + l15;
          atomicAdd(&scores[soff + (nrow + rr) * N + mcol], acc[fm][fn][rr]);
        }
      }
    }
    return;
  }
  // ---- sc0/sc1 path ----
  {
    auto As = (unsigned short (*)[136])(sbuf);
    auto Bs = (unsigned short (*)[136])(sbuf + 8704);
    int b2 = bid - 160;
    int sc, z, soff;
    if (b2 < 256) { sc = 0; z = b2;       soff = 0; }
    else          { sc = 1; z = b2 - 256; soff = 64; }
    int lw = 7 - sc, W = 1 << lw, lS = 14 - 2 * sc, N = 8 << (2 * sc);
    int kbase = z * 4096;
    floatx4 acc = zf;
    bool isA = tid < 128;
    int u = tid & 127;
    int srow = u >> 2, sslot0 = (u & 3) * 4;
    int grow = srow;
    int cb = (isA ? 0 : 256) + sc * 64;
    int pt = 0, sp0 = 0;
    bool valid = grow < N;
    if (valid) patch_row(grow, sc, lw, pt, sp0);
    int rowbase = (pt * 768 + cb) * 65536 + sp0;
    uintx4 r[4];
#define SLOAD(KS) { int kb2 = kbase + (KS) * 128; \
  _Pragma("unroll") for (int j = 0; j < 4; ++j) { \
    uintx4 v = zu; \
    if (valid) { int k = kb2 + (sslot0 + j) * 8; \
      int cl = k >> lS; int s = k & ((1 << lS) - 1); \
      int hh = s >> lw, ww = s & (W - 1); \
      v = *(const uintx4*)(qkv + rowbase + cl * 65536 + (hh << 8) + ww); } \
    r[j] = v; } }
    SLOAD(0);
    for (int ks = 0; ks < 32; ++ks) {
      __syncthreads();
      {
        unsigned short* dstrow = isA ? &As[srow][0] : &Bs[srow][0];
#pragma unroll
        for (int j = 0; j < 4; ++j) *(uintx4*)&dstrow[(sslot0 + j) * 8] = r[j];
      }
      __syncthreads();
      if (ks < 31) SLOAD(ks + 1);
#pragma unroll
      for (int kk = 0; kk < 4; ++kk) {
        short8 a = *(const short8*)&As[wr * 16 + l15][(kk * 4 + lhi) * 8];
        short8 b = *(const short8*)&Bs[wc * 16 + l15][(kk * 4 + lhi) * 8];
        acc = __builtin_amdgcn_mfma_f32_16x16x32_bf16(a, b, acc, 0, 0, 0);
      }
    }
#undef SLOAD
    int rrow = wr * 16 + lhi * 4;
    int ccol = wc * 16 + l15;
    if (ccol < N) {
#pragma unroll
      for (int rr = 0; rr < 4; ++rr)
        if (rrow + rr < N) atomicAdd(&scores[soff + (rrow + rr) * N + ccol], acc[rr]);
    }
  }
}

// ---------------- logits + softmax -> P bf16 ----------------
__global__ void k_softmax(const float* __restrict__ scores, const float* __restrict__ G,
                          const float* __restrict__ rbuf, const float* __restrict__ msc,
                          unsigned short* __restrict__ pbuf) {
  int row = blockIdx.x, lane = threadIdx.x;
  int sc, n, roff, soff, poff;
  if (row < 8)        { sc = 0; n = row;       roff = 0;   soff = 0;     poff = 0; }
  else if (row < 40)  { sc = 1; n = row - 8;   roff = 8;   soff = 64;    poff = 512; }
  else if (row < 168) { sc = 2; n = row - 40;  roff = 40;  soff = 1088;  poff = 1536; }
  else                { sc = 3; n = row - 168; roff = 168; soff = 17472; poff = 17920; }
  int N = 8 << (2 * sc);
  int Kpad = (sc < 2) ? 32 : N;
  float Sf = (float)(1 << (14 - 2 * sc));
  float invD = 1.0f / (float)(1 << (20 - 2 * sc));
  float alpha = msc[sc * 4 + 0], beta = msc[sc * 4 + 1];
  float gamma = msc[sc * 4 + 2], delta = msc[sc * 4 + 3];
  float rn = rbuf[roff + n];
  float vals[8];
  float mx = -1e30f;
#pragma unroll
  for (int j = 0; j < 8; ++j) {
    float v = -1e30f;
    int mcol = lane + j * 64;
    if (j * 64 < N && mcol < N) {
      float sq = scores[soff + n * N + mcol];
      float g = G[soff + n * N + mcol];
      float rm = rbuf[roff + mcol];
      v = sq * (alpha * g + beta * rn + gamma * rm + delta * Sf) * invD;
    }
    vals[j] = v;
    mx = fmaxf(mx, v);
  }
  for (int off = 32; off; off >>= 1) mx = fmaxf(mx, __shfl_xor(mx, off));
  float sum = 0.f;
#pragma unroll
  for (int j = 0; j < 8; ++j) {
    int mcol = lane + j * 64;
    float e = 0.f;
    if (j * 64 < N && mcol < N) e = __expf(vals[j] - mx);
    vals[j] = e;
    sum += e;
  }
  for (int off = 32; off; off >>= 1) sum += __shfl_xor(sum, off);
  float inv = 1.f / sum;
#pragma unroll
  for (int j = 0; j < 8; ++j) {
    int mcol = lane + j * 64;
    if (j * 64 < N && mcol < N) pbuf[poff + n * Kpad + mcol] = f2bf(vals[j] * inv);
  }
}

// ---------------- PV GEMM: dbuf LDS, 1 barrier/K-step, balanced XCD co-location ----------------
__global__ __launch_bounds__(256) void k_pv(const unsigned short* __restrict__ qkv,
                                            const unsigned short* __restrict__ pbuf,
                                            unsigned short* __restrict__ ynat) {
  int bid0 = blockIdx.x;
  int bid;
  if (bid0 < 6144) {
    bid = bid0;
  } else if (bid0 < 8192) {
    int q = bid0 - 6144; int c = q & 7, j = q >> 3;
    bid = 6144 + ((c * 128 + (j & 127)) << 1) + (j >> 7);
  } else {
    int q = bid0 - 8192; int c = q & 7, j = q >> 3;
    bid = 8192 + ((c * 32 + (j & 31)) << 3) + (j >> 5);
  }
  int sc, bx, by;
  if (bid < 4096)      { sc = 0; bx = bid; by = 0; }
  else if (bid < 6144) { sc = 1; bx = bid - 4096; by = 0; }
  else if (bid < 8192) { int r = bid - 6144; sc = 2; bx = r >> 1; by = r & 1; }
  else                 { int r = bid - 8192; sc = 3; bx = r >> 3; by = r & 7; }
  int WR    = (sc == 0) ? 1 : (sc == 1) ? 2 : 4;
  int logWC = (sc == 0) ? 2 : (sc == 1) ? 1 : 0;
  int poff  = (sc == 0) ? 0 : (sc == 1) ? 512 : (sc == 2) ? 1536 : 17920;
  int lw = 7 - sc, W = 1 << lw;
  int lS = 14 - 2 * sc;
  int N = 8 << (2 * sc);
  int Kpad = (sc < 2) ? 32 : N;
  int WC = 1 << logWC;
  int d0 = bx * (WC * 64);
  int nb = by * (WR * 16);
  __shared__ __align__(16) unsigned short As[2][64][40];
  __shared__ __align__(16) unsigned short Bt[2][256][32];
  int tid = threadIdx.x;
  int w = tid >> 6, l = tid & 63;
  int wr = w >> logWC, wc = w & (WC - 1);
  int l15 = l & 15, lhi = l >> 4;
  floatx4 zf = {0.f, 0.f, 0.f, 0.f};
  floatx4 acc[4];
#pragma unroll
  for (int i = 0; i < 4; ++i) acc[i] = zf;
  int bmp = tid & 15;
  int dg = tid >> 4;
  bool act0 = (WC > 1) || (dg < 8);
  bool has1 = (WC == 4);
  bool doA = tid < WR * 64;
  int arow = tid >> 2, akg = (tid & 3) * 8;
  int ksteps = Kpad >> 5;
  uintx4 zu = {0u, 0u, 0u, 0u};
  int vcb = (512 + sc * 64) * 65536;
  uintx4 av = zu, lo0 = zu, hi0 = zu, lo1 = zu, hi1 = zu;
#define PLOADS(KS) { int k0 = (KS) * 32; \
    av = zu; lo0 = zu; hi0 = zu; lo1 = zu; hi1 = zu; \
    if (doA) av = *(const uintx4*)(pbuf + poff + (nb + arow) * Kpad + k0 + akg); \
    int gm0 = k0 + 2 * bmp, gm1 = gm0 + 1; \
    bool mv0 = gm0 < N, mv1 = gm1 < N; \
    int pt0 = 0, sp00 = 0, pt1 = 0, sp01 = 0; \
    if (mv0) patch_row(gm0, sc, lw, pt0, sp00); \
    if (mv1) patch_row(gm1, sc, lw, pt1, sp01); \
    { int d = d0 + dg * 8; int cl = d >> lS; int s = d & ((1 << lS) - 1); \
      int hh = s >> lw, ww = s & (W - 1); int sp = (hh << 8) + ww; \
      if (act0 && mv0) lo0 = *(const uintx4*)(qkv + pt0 * 768 * 65536 + vcb + cl * 65536 + sp00 + sp); \
      if (act0 && mv1) hi0 = *(const uintx4*)(qkv + pt1 * 768 * 65536 + vcb + cl * 65536 + sp01 + sp); } \
    if (has1) { int d = d0 + (dg + 16) * 8; int cl = d >> lS; int s = d & ((1 << lS) - 1); \
      int hh = s >> lw, ww = s & (W - 1); int sp = (hh << 8) + ww; \
      if (mv0) lo1 = *(const uintx4*)(qkv + pt0 * 768 * 65536 + vcb + cl * 65536 + sp00 + sp); \
      if (mv1) hi1 = *(const uintx4*)(qkv + pt1 * 768 * 65536 + vcb + cl * 65536 + sp01 + sp); } }
  PLOADS(0);
  for (int ks = 0; ks < ksteps; ++ks) {
    int b = ks & 1;
    if (doA) *(uintx4*)&As[b][arow][akg] = av;
    if (act0) {
      int du = dg * 8;
#pragma unroll
      for (int j = 0; j < 8; ++j) {
        int d = du + j;
        unsigned losh = (lo0[j >> 1] >> ((j & 1) * 16)) & 0xFFFFu;
        unsigned hish = (hi0[j >> 1] >> ((j & 1) * 16)) & 0xFFFFu;
        unsigned wv = losh | (hish << 16);
        int slot = (bmp >> 2) ^ ((d >> 1) & 3) ^ ((d >> 3) & 3);
        ((unsigned int*)&Bt[b][d][0])[slot * 4 + (bmp & 3)] = wv;
      }
    }
    if (has1) {
      int du = (dg + 16) * 8;
#pragma unroll
      for (int j = 0; j < 8; ++j) {
        int d = du + j;
        unsigned losh = (lo1[j >> 1] >> ((j & 1) * 16)) & 0xFFFFu;
        unsigned hish = (hi1[j >> 1] >> ((j & 1) * 16)) & 0xFFFFu;
        unsigned wv = losh | (hish << 16);
        int slot = (bmp >> 2) ^ ((d >> 1) & 3) ^ ((d >> 3) & 3);
        ((unsigned int*)&Bt[b][d][0])[slot * 4 + (bmp & 3)] = wv;
      }
    }
    __syncthreads();
    if (ks + 1 < ksteps) PLOADS(ks + 1);
    short8 a = *(const short8*)&As[b][wr * 16 + l15][lhi * 8];
#pragma unroll
    for (int fn = 0; fn < 4; ++fn) {
      int row = wc * 64 + fn * 16 + l15;
      int slot = lhi ^ ((row >> 1) & 3) ^ ((row >> 3) & 3);
      short8 bb = *(const short8*)&Bt[b][row][slot * 8];
      acc[fn] = __builtin_amdgcn_mfma_f32_16x16x32_bf16(a, bb, acc[fn], 0, 0, 0);
    }
  }
#undef PLOADS
  int nrow = nb + wr * 16 + lhi * 4;
#pragma unroll
  for (int rr = 0; rr < 4; ++rr) {
    int n = nrow + rr;
    if (n < N) {
      int pt, sp0;
      patch_row(n, sc, lw, pt, sp0);
#pragma unroll
      for (int fn = 0; fn < 4; ++fn) {
        int d = d0 + wc * 64 + fn * 16 + l15;
        int cl = d >> lS;
        int s = d & ((1 << lS) - 1);
        int hh = s >> lw, ww = s & (W - 1);
        int c = sc * 64 + cl;
        ynat[(pt * 256 + c) * 65536 + sp0 + (hh << 8) + ww] = f2bf(acc[fn][rr]);
      }
    }
  }
}

// ---------------- conv3x3: halo-row staging (R9, known-good 187us) ----------------
__global__ __launch_bounds__(256, 2) void k_conv(const unsigned short* __restrict__ yt,
                                                 const unsigned short* __restrict__ wo,
                                                 const float* __restrict__ bo,
                                                 float* __restrict__ out) {
  __shared__ __align__(16) unsigned short As[128][128];
  __shared__ __align__(16) unsigned short Bs[130][64];
  int flat = blockIdx.x;
  int lg = ((flat & 7) << 7) + (flat >> 3);
  int n_t = lg >> 1, m_t = lg & 1;
  int n0 = n_t << 8, m0 = m_t << 7;
  int tt = n0 >> 16, yy = (n0 >> 8) & 255;
  int tid = threadIdx.x;
  int w = tid >> 6, l = tid & 63;
  int wr = w >> 1, wc = w & 1;
  int l15 = l & 15, lhi = l >> 4;
  int a_d0 = tid >> 7, a_o0 = tid & 127;
  bool doA1 = tid < 128;
  bool doBh = tid >= 254;
  floatx4 zf = {0.f, 0.f, 0.f, 0.f};
  floatx4 acc[4][8];
#pragma unroll
  for (int i = 0; i < 4; ++i)
#pragma unroll
    for (int j = 0; j < 8; ++j) acc[i][j] = zf;
  uintx4 zu = {0u, 0u, 0u, 0u};
  uintx4 rb[4], ra0[4], ra1[4];
  const unsigned short* ybase = yt + (tt << 24);
#define CLOAD(ST) { \
    int dy = (ST) >> 3, cc = ((ST) & 7) << 5; \
    int yq = yy + dy - 1; \
    bool yv = (unsigned)yq < 256u; \
    { int xq = tid - 1; \
      if (yv && (unsigned)xq < 256u) { \
        const uintx4* p = (const uintx4*)(ybase + ((yq << 8) + xq) * 256 + cc); \
        rb[0] = p[0]; rb[1] = p[1]; rb[2] = p[2]; rb[3] = p[3]; \
      } else { rb[0] = zu; rb[1] = zu; rb[2] = zu; rb[3] = zu; } } \
    { const uintx4* p = (const uintx4*)(wo + (dy * 3 + a_d0) * 65536 + (m0 + a_o0) * 256 + cc); \
      ra0[0] = p[0]; ra0[1] = p[1]; ra0[2] = p[2]; ra0[3] = p[3]; } \
    if (doA1) { \
      const uintx4* p = (const uintx4*)(wo + (dy * 3 + 2) * 65536 + (m0 + tid) * 256 + cc); \
      ra1[0] = p[0]; ra1[1] = p[1]; ra1[2] = p[2]; ra1[3] = p[3]; \
    } else if (doBh) { \
      int xq = tid + 1; \
      if (yv && xq < 256) { \
        const uintx4* p = (const uintx4*)(ybase + ((yq << 8) + xq) * 256 + cc); \
        ra1[0] = p[0]; ra1[1] = p[1]; ra1[2] = p[2]; ra1[3] = p[3]; \
      } else { ra1[0] = zu; ra1[1] = zu; ra1[2] = zu; ra1[3] = zu; } } }
  CLOAD(0);
  for (int st = 0; st < 24; ++st) {
    __syncthreads();
    {
      int brow = tid >> 1, bhf = (tid & 1) * 4, br7 = brow & 7;
#pragma unroll
      for (int j = 0; j < 4; ++j)
        *(uintx4*)&Bs[brow][((bhf + j) ^ br7) * 8] = rb[j];
      int ao7 = a_o0 & 7;
#pragma unroll
      for (int j = 0; j < 4; ++j)
        *(uintx4*)&As[a_o0][((a_d0 * 4 + j) ^ ao7) * 8] = ra0[j];
      if (doA1) {
        int o7 = tid & 7;
#pragma unroll
        for (int j = 0; j < 4; ++j)
          *(uintx4*)&As[tid][((8 + j) ^ o7) * 8] = ra1[j];
      } else if (doBh) {
        int xh = tid + 2;
        int brow2 = xh >> 1, bhf2 = (xh & 1) * 4, br72 = brow2 & 7;
#pragma unroll
        for (int j = 0; j < 4; ++j)
          *(uintx4*)&Bs[brow2][((bhf2 + j) ^ br72) * 8] = ra1[j];
      }
    }
    __syncthreads();
    if (st < 23) CLOAD(st + 1);
#pragma unroll
    for (int dx = 0; dx < 3; ++dx) {
      short8 af[4];
#pragma unroll
      for (int f = 0; f < 4; ++f) {
        int ol = wr * 64 + f * 16 + l15;
        af[f] = *(const short8*)&As[ol][((dx * 4 + lhi) ^ (ol & 7)) * 8];
      }
#pragma unroll
      for (int fn = 0; fn < 8; ++fn) {
        int xh = wc * 128 + fn * 16 + l15 + dx;
        short8 b = *(const short8*)&Bs[xh >> 1][((((xh & 1) * 4 + lhi)) ^ ((xh >> 1) & 7)) * 8];
#pragma unroll
        for (int fm = 0; fm < 4; ++fm)
          acc[fm][fn] = __builtin_amdgcn_mfma_f32_16x16x32_bf16(af[fm], b, acc[fm][fn], 0, 0, 0);
      }
    }
  }
#undef CLOAD
#pragma unroll
  for (int fm = 0; fm < 4; ++fm) {
    int o = m0 + wr * 64 + fm * 16 + lhi * 4;
#pragma unroll
    for (int rr = 0; rr < 4; ++rr) {
      float bias = bo[o + rr];
#pragma unroll
      for (int fn = 0; fn < 8; ++fn) {
        int xcol = wc * 128 + fn * 16 + l15;
        float z = acc[fm][fn][rr] + bias;
        out[((tt * 256 + o + rr) << 16) + (yy << 8) + xcol] = z > 0.f ? z : 0.2f * z;
      }
    }
  }
}

// ---------------------------------------------------------------------------
extern "C" void kernel_launch(void* const* d_in, const int* in_sizes, int n_in,
                              void* d_out, int out_size, void* d_ws, size_t ws_size,
                              hipStream_t stream) {
  const float* x   = (const float*)d_in[0];
  const float* m   = (const float*)d_in[1];
  const float* Wq  = (const float*)d_in[2];
  const float* bq  = (const float*)d_in[3];
  const float* Wk  = (const float*)d_in[4];
  const float* bk  = (const float*)d_in[5];
  const float* Wv  = (const float*)d_in[6];
  const float* bv  = (const float*)d_in[7];
  const float* Wmq = (const float*)d_in[8];
  const float* bmq = (const float*)d_in[9];
  const float* Wmk = (const float*)d_in[10];
  const float* bmk = (const float*)d_in[11];
  const float* Wo  = (const float*)d_in[12];
  const float* bo  = (const float*)d_in[13];

  char* ws = (char*)d_ws;
  unsigned short* qkv   = (unsigned short*)(ws);
  unsigned short* xtb   = (unsigned short*)(ws + 201326592);  // xt, later yt
  unsigned short* wqkv  = (unsigned short*)(ws + 268435456);
  unsigned short* wobf  = (unsigned short*)(ws + 268828672);
  float* bias           = (float*)(ws + 270008320);
  float* msc            = (float*)(ws + 270011392);
  float* scores         = (float*)(ws + 270011456);
  float* G              = (float*)(ws + 271129920);
  float* rbuf           = (float*)(ws + 272248384);
  unsigned short* pbuf  = (unsigned short*)(ws + 272251104);
  float* out            = (float*)d_out;
  unsigned short* ynat  = (unsigned short*)d_out;  // low half of d_out as bf16 scratch

  k_prep<<<dim3(5258), dim3(256), 0, stream>>>(Wq, Wk, Wv, bq, bk, bv, Wmq, bmq, Wmk, bmk,
                                               Wo, wqkv, bias, msc, wobf, scores,
                                               (unsigned int*)pbuf);
  k_xtm<<<dim3(8690), dim3(256), 0, stream>>>(x, xtb, m, G, rbuf);
  k_qkv<<<dim3(3072), dim3(256), 49152, stream>>>(xtb, wqkv, bias, qkv);
  k_scores_all<<<dim3(480), dim3(256), 0, stream>>>(qkv, scores);
  k_softmax<<<dim3(680), dim3(64), 0, stream>>>(scores, G, rbuf, msc, pbuf);
  k_pv<<<dim3(10240), dim3(256), 0, stream>>>(qkv, pbuf, ynat);
  k_yt<<<dim3(1024, 4, 2), dim3(256), 0, stream>>>(ynat, xtb);
  k_conv<<<dim3(1024), dim3(256), 0, stream>>>(xtb, wobf, bo, out);
}

// Round 15
// 524.445 us; speedup vs baseline: 1.1045x; 1.0016x over previous
//
#include <hip/hip_runtime.h>
#include <stdint.h>

// ---------------------------------------------------------------------------
// MultiHeadedAttention (4-scale patch attention) for MI355X / gfx950
// R15: R14 + T5 s_setprio(1/0) around MFMA clusters in k_conv/k_qkv/k_pv
//      (2+ blocks/CU at independent phases = role diversity -> T5 applies).
// ---------------------------------------------------------------------------

typedef __attribute__((ext_vector_type(8))) short short8;
typedef __attribute__((ext_vector_type(4))) float floatx4;
typedef __attribute__((ext_vector_type(4))) unsigned int uintx4;

#define DEV static __device__ __forceinline__

DEV unsigned short f2bf(float f) {
  unsigned u = __builtin_bit_cast(unsigned, f);
  unsigned r = u + 0x7FFFu + ((u >> 16) & 1u);
  return (unsigned short)(r >> 16);
}

DEV void patch_row(int n, int sc, int lw, int& pt, int& sp0) {
  pt = n >> (2 + 2 * sc);
  int rem = n & ((4 << (2 * sc)) - 1);
  int oh = rem >> (1 + sc), ow = rem & ((2 << sc) - 1);
  sp0 = (oh << (lw + 8)) + (ow << lw);
}

// ---------------- merged prep: weights + mask scalars + Wo repack + zeroing ----------------
__global__ __launch_bounds__(256) void k_prep(const float* __restrict__ Wq, const float* __restrict__ Wk,
                       const float* __restrict__ Wv, const float* __restrict__ bq,
                       const float* __restrict__ bk, const float* __restrict__ bv,
                       const float* __restrict__ Wmq, const float* __restrict__ bmq,
                       const float* __restrict__ Wmk, const float* __restrict__ bmk,
                       const float* __restrict__ Wo,
                       unsigned short* __restrict__ wqkv, float* __restrict__ bias,
                       float* __restrict__ msc, unsigned short* __restrict__ wobf,
                       float* __restrict__ scoresG, unsigned int* __restrict__ pbuf) {
  int bid = blockIdx.x;
  int t = threadIdx.x;
  if (bid < 768) {
    const float* src = bid < 256 ? (Wq + bid * 256) : (bid < 512 ? (Wk + (bid - 256) * 256)
                                                                 : (Wv + (bid - 512) * 256));
    wqkv[bid * 256 + t] = f2bf(src[t]);
    if (t == 0) bias[bid] = bid < 256 ? bq[bid] : (bid < 512 ? bk[bid - 256] : bv[bid - 512]);
    return;
  }
  if (bid == 768) {
    int sc = t >> 6, lane = t & 63;
    int ch = sc * 64 + lane;
    float a0 = Wmq[ch] * Wmk[ch];
    float a1 = Wmq[ch] * bmk[ch];
    float a2 = bmq[ch] * Wmk[ch];
    float a3 = bmq[ch] * bmk[ch];
    for (int off = 32; off; off >>= 1) {
      a0 += __shfl_xor(a0, off); a1 += __shfl_xor(a1, off);
      a2 += __shfl_xor(a2, off); a3 += __shfl_xor(a3, off);
    }
    if (lane == 0) {
      msc[sc * 4 + 0] = a0; msc[sc * 4 + 1] = a1;
      msc[sc * 4 + 2] = a2; msc[sc * 4 + 3] = a3;
    }
    return;
  }
  int blk = bid - 769;
  if (blk < 2304) {
    int didx = blk >> 8, o = blk & 255, c = t;
    wobf[didx * 65536 + o * 256 + c] = f2bf(Wo[o * 2304 + c * 9 + didx]);
  } else {
    int i = (blk - 2304) * 256 + t;
    if (i < 559232) scoresG[i] = 0.f;
    if (i < 140032) pbuf[i] = 0u;
  }
}

// ---------------- x transpose (bid<8192) + mask gram/rowsum (bid>=8192) ----------------
__global__ __launch_bounds__(256) void k_xtm(const float* __restrict__ x,
                                             unsigned short* __restrict__ xt,
                                             const float* __restrict__ m,
                                             float* __restrict__ G,
                                             float* __restrict__ rbuf) {
  int bid = blockIdx.x;
  int tid = threadIdx.x;
  if (bid < 8192) {
    __shared__ __align__(16) unsigned short tile[64][72];
    int p0 = (bid & 1023) * 64, c0 = ((bid >> 10) & 3) * 64, t = bid >> 12;
    {
      int cc = tid >> 2, pq = (tid & 3) * 16;
      const float* src = x + ((t * 256 + c0 + cc) * 65536 + p0 + pq);
      __align__(16) unsigned short tmp[16];
#pragma unroll
      for (int e = 0; e < 16; e += 4) {
        floatx4 v = *(const floatx4*)(src + e);
        tmp[e + 0] = f2bf(v[0]); tmp[e + 1] = f2bf(v[1]);
        tmp[e + 2] = f2bf(v[2]); tmp[e + 3] = f2bf(v[3]);
      }
      *(uintx4*)&tile[cc][pq] = *(const uintx4*)&tmp[0];
      *(uintx4*)&tile[cc][pq + 8] = *(const uintx4*)&tmp[8];
    }
    __syncthreads();
    {
      int pp = tid >> 2, cg = (tid & 3) * 16;
      __align__(16) unsigned short outv[16];
#pragma unroll
      for (int e = 0; e < 16; ++e) outv[e] = tile[cg + e][pp];
      unsigned short* dst = xt + ((t * 65536 + p0 + pp) * 256 + c0 + cg);
      *(uintx4*)dst = *(const uintx4*)&outv[0];
      *(uintx4*)(dst + 8) = *(const uintx4*)&outv[8];
    }
    return;
  }
  int mb = bid - 8192;
  if (mb >= 328) {
    int row = (mb - 328) * 4 + (tid >> 6);
    int lane = tid & 63;
    if (row < 680) {
      int sc, n;
      if (row < 8)        { sc = 0; n = row; }
      else if (row < 40)  { sc = 1; n = row - 8; }
      else if (row < 168) { sc = 2; n = row - 40; }
      else                { sc = 3; n = row - 168; }
      int lw = 7 - sc, W = 1 << lw;
      int pt, sp0;
      patch_row(n, sc, lw, pt, sp0);
      int base = pt * 65536 + sp0;
      int S = 1 << (14 - 2 * sc);
      float acc = 0.f;
      for (int s = lane; s < S; s += 64) {
        int hh = s >> lw, ww = s & (W - 1);
        acc += m[base + (hh << 8) + ww];
      }
      for (int off = 32; off; off >>= 1) acc += __shfl_xor(acc, off);
      if (lane == 0) rbuf[row] = acc;
    }
    return;
  }
  __shared__ __align__(16) float Ns[32][68];
  __shared__ __align__(16) float Ms[32][68];
  int sc, tn, tm, z, nchunks, soff;
  if (mb < 32)      { sc = 0; tn = 0; tm = 0; z = mb;      nchunks = 8; soff = 0; }
  else if (mb < 40) { sc = 1; tn = 0; tm = 0; z = mb - 32; nchunks = 8; soff = 64; }
  else if (mb < 72) { int r = mb - 40; int tl = r >> 1; sc = 2; tn = tl >> 2; tm = tl & 3; z = r & 1; nchunks = 8; soff = 1088; }
  else              { int tl = mb - 72; sc = 3; tn = tl >> 4; tm = tl & 15; z = 0; nchunks = 4; soff = 17472; }
  int lw = 7 - sc, W = 1 << lw, N = 8 << (2 * sc);
  int kbase = z * nchunks * 64;
  int n0 = tn * 32, m0 = tm * 32;
  bool isA = tid < 128;
  int u = tid & 127;
  int srow = u >> 2, sslot0 = (u & 3) * 4;
  int grow = (isA ? n0 : m0) + srow;
  bool valid = grow < N;
  int pt = 0, sp0 = 0;
  if (valid) patch_row(grow, sc, lw, pt, sp0);
  int gbase = pt * 65536 + sp0;
  int trc = tid >> 4, tcc = tid & 15;
  float a00 = 0.f, a01 = 0.f, a10 = 0.f, a11 = 0.f;
  floatx4 zf = {0.f, 0.f, 0.f, 0.f};
  for (int c = 0; c < nchunks; ++c) {
    int k0 = kbase + c * 64;
    floatx4 v[4];
#pragma unroll
    for (int j = 0; j < 4; ++j) {
      v[j] = zf;
      if (valid) {
        int s = k0 + (sslot0 + j) * 4;
        int hh = s >> lw, ww = s & (W - 1);
        v[j] = *(const floatx4*)(m + gbase + (hh << 8) + ww);
      }
    }
    __syncthreads();
    float* dstrow = isA ? &Ns[srow][0] : &Ms[srow][0];
#pragma unroll
    for (int j = 0; j < 4; ++j) *(floatx4*)&dstrow[(sslot0 + j) * 4] = v[j];
    __syncthreads();
#pragma unroll 4
    for (int k = 0; k < 64; k += 4) {
      floatx4 na = *(const floatx4*)&Ns[2 * trc][k];
      floatx4 nb = *(const floatx4*)&Ns[2 * trc + 1][k];
      floatx4 ma = *(const floatx4*)&Ms[2 * tcc][k];
      floatx4 mb2 = *(const floatx4*)&Ms[2 * tcc + 1][k];
#pragma unroll
      for (int e = 0; e < 4; ++e) {
        a00 += na[e] * ma[e]; a01 += na[e] * mb2[e];
        a10 += nb[e] * ma[e]; a11 += nb[e] * mb2[e];
      }
    }
  }
  int rn = n0 + 2 * trc, rm = m0 + 2 * tcc;
  float res[2][2] = {{a00, a01}, {a10, a11}};
#pragma unroll
  for (int i = 0; i < 2; ++i)
#pragma unroll
    for (int j = 0; j < 2; ++j) {
      if (rn + i < N && rm + j < N) {
        float* dst = &G[soff + (rn + i) * N + rm + j];
        if (sc < 3) atomicAdd(dst, res[i][j]); else *dst = res[i][j];
      }
    }
}

// ---------------- y transpose ----------------
__global__ __launch_bounds__(256) void k_yt(const unsigned short* __restrict__ ynat,
                                            unsigned short* __restrict__ yt) {
  __shared__ __align__(16) unsigned short tile[64][72];
  int p0 = blockIdx.x * 64, c0 = blockIdx.y * 64, t = blockIdx.z;
  int tid = threadIdx.x;
  {
    int cc = tid >> 2, pq = (tid & 3) * 16;
    const unsigned short* src = ynat + ((t * 256 + c0 + cc) * 65536 + p0 + pq);
    *(uintx4*)&tile[cc][pq] = *(const uintx4*)src;
    *(uintx4*)&tile[cc][pq + 8] = *(const uintx4*)(src + 8);
  }
  __syncthreads();
  {
    int pp = tid >> 2, cg = (tid & 3) * 16;
    __align__(16) unsigned short outv[16];
#pragma unroll
    for (int e = 0; e < 16; ++e) outv[e] = tile[cg + e][pp];
    unsigned short* dst = yt + ((t * 65536 + p0 + pp) * 256 + c0 + cg);
    *(uintx4*)dst = *(const uintx4*)&outv[0];
    *(uintx4*)(dst + 8) = *(const uintx4*)&outv[8];
  }
}

// ---------------- QKV GEMM: 128x256 tile + LDS-transposed coalesced epilogue ----------------
__global__ __launch_bounds__(256, 2) void k_qkv(const unsigned short* __restrict__ xt,
                                                const unsigned short* __restrict__ wqkv,
                                                const float* __restrict__ bias,
                                                unsigned short* __restrict__ qkv) {
  extern __shared__ __align__(16) char smem[];
  auto As = (unsigned short (*)[64])(smem);            // [128][64]  16KB
  auto Bs = (unsigned short (*)[64])(smem + 16384);    // [256][64]  32KB
  auto Cs = (unsigned short (*)[280])(smem);           // [64][280]  35KB (overlay)
  int flat = blockIdx.x;
  int lg = (flat & 7) * 384 + (flat >> 3);
  int n_t = lg / 6, m_t = lg - n_t * 6;
  int n0 = n_t << 8, m0 = m_t << 7;
  int tid = threadIdx.x;
  int w = tid >> 6, l = tid & 63;
  int wr = w >> 1, wc = w & 1;
  int l15 = l & 15, lhi = l >> 4;
  int sr = tid >> 1, sbase = (tid & 1) * 4, r7 = sr & 7;
  int b7 = tid & 7;
  const unsigned short* gA = wqkv + (m0 + sr) * 256 + sbase * 8;
  const unsigned short* gB = xt + (n0 + tid) * 256;
  floatx4 zf = {0.f, 0.f, 0.f, 0.f};
  floatx4 acc[4][8];
#pragma unroll
  for (int i = 0; i < 4; ++i)
#pragma unroll
    for (int j = 0; j < 8; ++j) acc[i][j] = zf;
  uintx4 ra[4], rb[8];
#define QLOAD(K0) { const uintx4* pa = (const uintx4*)(gA + (K0)); \
                    ra[0] = pa[0]; ra[1] = pa[1]; ra[2] = pa[2]; ra[3] = pa[3]; \
                    const uintx4* pb = (const uintx4*)(gB + (K0)); \
                    rb[0] = pb[0]; rb[1] = pb[1]; rb[2] = pb[2]; rb[3] = pb[3]; \
                    rb[4] = pb[4]; rb[5] = pb[5]; rb[6] = pb[6]; rb[7] = pb[7]; }
  QLOAD(0);
#pragma unroll
  for (int ch = 0; ch < 4; ++ch) {
    __syncthreads();
#pragma unroll
    for (int j = 0; j < 4; ++j)
      *(uintx4*)&As[sr][((sbase + j) ^ r7) * 8] = ra[j];
#pragma unroll
    for (int j = 0; j < 8; ++j)
      *(uintx4*)&Bs[tid][(j ^ b7) * 8] = rb[j];
    __syncthreads();
    if (ch < 3) QLOAD((ch + 1) * 64);
#pragma unroll
    for (int kk = 0; kk < 2; ++kk) {
      short8 af[4];
#pragma unroll
      for (int f = 0; f < 4; ++f) {
        int arow = wr * 64 + f * 16 + l15;
        af[f] = *(const short8*)&As[arow][(((kk << 2) + lhi) ^ (arow & 7)) * 8];
      }
      __builtin_amdgcn_s_setprio(1);
#pragma unroll
      for (int fn = 0; fn < 8; ++fn) {
        int brow = wc * 128 + fn * 16 + l15;
        short8 b = *(const short8*)&Bs[brow][(((kk << 2) + lhi) ^ (brow & 7)) * 8];
#pragma unroll
        for (int fm = 0; fm < 4; ++fm)
          acc[fm][fn] = __builtin_amdgcn_mfma_f32_16x16x32_bf16(af[fm], b, acc[fm][fn], 0, 0, 0);
      }
      __builtin_amdgcn_s_setprio(0);
    }
  }
#undef QLOAD
#pragma unroll
  for (int h = 0; h < 2; ++h) {
    __syncthreads();
    if (wr == h) {
#pragma unroll
      for (int fm = 0; fm < 4; ++fm) {
#pragma unroll
        for (int rr = 0; rr < 4; ++rr) {
          int rl = fm * 16 + lhi * 4 + rr;
          float bv = bias[m0 + h * 64 + rl];
#pragma unroll
          for (int fn = 0; fn < 8; ++fn)
            Cs[rl][wc * 128 + fn * 16 + l15] = f2bf(acc[fm][fn][rr] + bv);
        }
      }
    }
    __syncthreads();
    {
      int p8 = (tid & 31) * 8;
      int pcol = n0 + p8;
      int t = pcol >> 16, p = pcol & 65535;
#pragma unroll
      for (int pass = 0; pass < 8; ++pass) {
        int rl = (tid >> 5) + pass * 8;
        uintx4 v = *(const uintx4*)&Cs[rl][p8];
        *(uintx4*)&qkv[((t * 768 + m0 + h * 64 + rl) << 16) + p] = v;
      }
    }
  }
}

// ---------------- merged scores: bid<160 big (sc2/sc3), else 32x32 (sc0/sc1) ----------------
__global__ __launch_bounds__(256) void k_scores_all(const unsigned short* __restrict__ qkv,
                                                    float* __restrict__ scores) {
  __shared__ __align__(16) char sbuf[32768];
  int bid = blockIdx.x;
  int tid = threadIdx.x;
  int w = tid >> 6, l = tid & 63;
  int wr = w >> 1, wc = w & 1, l15 = l & 15, lhi = l >> 4;
  uintx4 zu = {0u, 0u, 0u, 0u};
  floatx4 zf = {0.f, 0.f, 0.f, 0.f};
  if (bid < 160) {
    auto As = (unsigned short (*)[64])(sbuf);
    auto Bs = (unsigned short (*)[64])(sbuf + 16384);
    int lg = (bid & 7) * 20 + (bid >> 3);
    int sc, tn, tm, z, soff;
    if (lg < 32) { sc = 2; tn = 0; tm = 0; z = lg; soff = 1088; }
    else { int r = lg - 32; int tl = r >> 3; sc = 3; tn = tl >> 2; tm = tl & 3; z = r & 7; soff = 17472; }
    int N = 8 << (2 * sc);
    int lw = 7 - sc, W = 1 << lw, lS = 14 - 2 * sc;
    int n0 = tn * 128, m0 = tm * 128;
    int kbase = z * 2048;
    int sr = tid >> 1, sbase = (tid & 1) * 4, r7 = sr & 7;
    int ptA, spA, ptB, spB;
    patch_row(n0 + sr, sc, lw, ptA, spA);
    patch_row(m0 + sr, sc, lw, ptB, spB);
    int baseA = (ptA * 768 + sc * 64) * 65536 + spA;
    int baseB = (ptB * 768 + 256 + sc * 64) * 65536 + spB;
    floatx4 acc[4][4];
#pragma unroll
    for (int i = 0; i < 4; ++i)
#pragma unroll
      for (int j = 0; j < 4; ++j) acc[i][j] = zf;
    uintx4 ra[4], rb[4];
#define GLOAD(K0) { \
  _Pragma("unroll") for (int j = 0; j < 4; ++j) { \
    int k = kbase + (K0) + (sbase + j) * 8; \
    int cl = k >> lS; int s = k & ((1 << lS) - 1); \
    int hh = s >> lw, ww = s & (W - 1); \
    int off = cl * 65536 + (hh << 8) + ww; \
    ra[j] = *(const uintx4*)(qkv + baseA + off); \
    rb[j] = *(const uintx4*)(qkv + baseB + off); } }
    GLOAD(0);
    for (int st = 0; st < 32; ++st) {
      __syncthreads();
#pragma unroll
      for (int j = 0; j < 4; ++j) {
        *(uintx4*)&As[sr][((sbase + j) ^ r7) * 8] = ra[j];
        *(uintx4*)&Bs[sr][((sbase + j) ^ r7) * 8] = rb[j];
      }
      __syncthreads();
      if (st < 31) GLOAD((st + 1) * 64);
#pragma unroll
      for (int kk = 0; kk < 2; ++kk) {
        short8 af[4], bfr[4];
#pragma unroll
        for (int f = 0; f < 4; ++f) {
          int arow = wr * 64 + f * 16 + l15;
          af[f] = *(const short8*)&As[arow][(((kk << 2) + lhi) ^ (arow & 7)) * 8];
          int brow = wc * 64 + f * 16 + l15;
          bfr[f] = *(const short8*)&Bs[brow][(((kk << 2) + lhi) ^ (brow & 7)) * 8];
        }
#pragma unroll
        for (int fm = 0; fm < 4; ++fm)
#pragma unroll
          for (int fn = 0; fn < 4; ++fn)
            acc[fm][fn] = __builtin_amdgcn_mfma_f32_16x16x32_bf16(af[fm], bfr[fn], acc[fm][fn], 0, 0, 0);
      }
    }
#undef GLOAD
#pragma unroll
    for (int fm = 0; fm < 4; ++fm) {
      int nrow = n0 + wr * 64 + fm * 16 + lhi * 4;
#pragma unroll
      for (int rr = 0; rr < 4; ++rr) {
#pragma unroll
        for (int fn = 0; fn < 4; ++fn) {
          int mcol = m0 + wc * 64 + fn * 16 + l15;
          atomicAdd(&scores[soff + (nrow + rr) * N + mcol], acc[fm][fn][rr]);
        }
      }
    }
    return;
  }
  // ---- sc0/sc1 path ----
  {
    auto As = (unsigned short (*)[136])(sbuf);
    auto Bs = (unsigned short (*)[136])(sbuf + 8704);
    int b2 = bid - 160;
    int sc, z, soff;
    if (b2 < 256) { sc = 0; z = b2;       soff = 0; }
    else          { sc = 1; z = b2 - 256; soff = 64; }
    int lw = 7 - sc, W = 1 << lw, lS = 14 - 2 * sc, N = 8 << (2 * sc);
    int kbase = z * 4096;
    floatx4 acc = zf;
    bool isA = tid < 128;
    int u = tid & 127;
    int srow = u >> 2, sslot0 = (u & 3) * 4;
    int grow = srow;
    int cb = (isA ? 0 : 256) + sc * 64;
    int pt = 0, sp0 = 0;
    bool valid = grow < N;
    if (valid) patch_row(grow, sc, lw, pt, sp0);
    int rowbase = (pt * 768 + cb) * 65536 + sp0;
    uintx4 r[4];
#define SLOAD(KS) { int kb2 = kbase + (KS) * 128; \
  _Pragma("unroll") for (int j = 0; j < 4; ++j) { \
    uintx4 v = zu; \
    if (valid) { int k = kb2 + (sslot0 + j) * 8; \
      int cl = k >> lS; int s = k & ((1 << lS) - 1); \
      int hh = s >> lw, ww = s & (W - 1); \
      v = *(const uintx4*)(qkv + rowbase + cl * 65536 + (hh << 8) + ww); } \
    r[j] = v; } }
    SLOAD(0);
    for (int ks = 0; ks < 32; ++ks) {
      __syncthreads();
      {
        unsigned short* dstrow = isA ? &As[srow][0] : &Bs[srow][0];
#pragma unroll
        for (int j = 0; j < 4; ++j) *(uintx4*)&dstrow[(sslot0 + j) * 8] = r[j];
      }
      __syncthreads();
      if (ks < 31) SLOAD(ks + 1);
#pragma unroll
      for (int kk = 0; kk < 4; ++kk) {
        short8 a = *(const short8*)&As[wr * 16 + l15][(kk * 4 + lhi) * 8];
        short8 b = *(const short8*)&Bs[wc * 16 + l15][(kk * 4 + lhi) * 8];
        acc = __builtin_amdgcn_mfma_f32_16x16x32_bf16(a, b, acc, 0, 0, 0);
      }
    }
#undef SLOAD
    int rrow = wr * 16 + lhi * 4;
    int ccol = wc * 16 + l15;
    if (ccol < N) {
#pragma unroll
      for (int rr = 0; rr < 4; ++rr)
        if (rrow + rr < N) atomicAdd(&scores[soff + (rrow + rr) * N + ccol], acc[rr]);
    }
  }
}

// ---------------- logits + softmax -> P bf16 ----------------
__global__ void k_softmax(const float* __restrict__ scores, const float* __restrict__ G,
                          const float* __restrict__ rbuf, const float* __restrict__ msc,
                          unsigned short* __restrict__ pbuf) {
  int row = blockIdx.x, lane = threadIdx.x;
  int sc, n, roff, soff, poff;
  if (row < 8)        { sc = 0; n = row;       roff = 0;   soff = 0;     poff = 0; }
  else if (row < 40)  { sc = 1; n = row - 8;   roff = 8;   soff = 64;    poff = 512; }
  else if (row < 168) { sc = 2; n = row - 40;  roff = 40;  soff = 1088;  poff = 1536; }
  else                { sc = 3; n = row - 168; roff = 168; soff = 17472; poff = 17920; }
  int N = 8 << (2 * sc);
  int Kpad = (sc < 2) ? 32 : N;
  float Sf = (float)(1 << (14 - 2 * sc));
  float invD = 1.0f / (float)(1 << (20 - 2 * sc));
  float alpha = msc[sc * 4 + 0], beta = msc[sc * 4 + 1];
  float gamma = msc[sc * 4 + 2], delta = msc[sc * 4 + 3];
  float rn = rbuf[roff + n];
  float vals[8];
  float mx = -1e30f;
#pragma unroll
  for (int j = 0; j < 8; ++j) {
    float v = -1e30f;
    int mcol = lane + j * 64;
    if (j * 64 < N && mcol < N) {
      float sq = scores[soff + n * N + mcol];
      float g = G[soff + n * N + mcol];
      float rm = rbuf[roff + mcol];
      v = sq * (alpha * g + beta * rn + gamma * rm + delta * Sf) * invD;
    }
    vals[j] = v;
    mx = fmaxf(mx, v);
  }
  for (int off = 32; off; off >>= 1) mx = fmaxf(mx, __shfl_xor(mx, off));
  float sum = 0.f;
#pragma unroll
  for (int j = 0; j < 8; ++j) {
    int mcol = lane + j * 64;
    float e = 0.f;
    if (j * 64 < N && mcol < N) e = __expf(vals[j] - mx);
    vals[j] = e;
    sum += e;
  }
  for (int off = 32; off; off >>= 1) sum += __shfl_xor(sum, off);
  float inv = 1.f / sum;
#pragma unroll
  for (int j = 0; j < 8; ++j) {
    int mcol = lane + j * 64;
    if (j * 64 < N && mcol < N) pbuf[poff + n * Kpad + mcol] = f2bf(vals[j] * inv);
  }
}

// ---------------- PV GEMM: dbuf LDS, 1 barrier/K-step, balanced XCD co-location ----------------
__global__ __launch_bounds__(256) void k_pv(const unsigned short* __restrict__ qkv,
                                            const unsigned short* __restrict__ pbuf,
                                            unsigned short* __restrict__ ynat) {
  int bid0 = blockIdx.x;
  int bid;
  if (bid0 < 6144) {
    bid = bid0;
  } else if (bid0 < 8192) {
    int q = bid0 - 6144; int c = q & 7, j = q >> 3;
    bid = 6144 + ((c * 128 + (j & 127)) << 1) + (j >> 7);
  } else {
    int q = bid0 - 8192; int c = q & 7, j = q >> 3;
    bid = 8192 + ((c * 32 + (j & 31)) << 3) + (j >> 5);
  }
  int sc, bx, by;
  if (bid < 4096)      { sc = 0; bx = bid; by = 0; }
  else if (bid < 6144) { sc = 1; bx = bid - 4096; by = 0; }
  else if (bid < 8192) { int r = bid - 6144; sc = 2; bx = r >> 1; by = r & 1; }
  else                 { int r = bid - 8192; sc = 3; bx = r >> 3; by = r & 7; }
  int WR    = (sc == 0) ? 1 : (sc == 1) ? 2 : 4;
  int logWC = (sc == 0) ? 2 : (sc == 1) ? 1 : 0;
  int poff  = (sc == 0) ? 0 : (sc == 1) ? 512 : (sc == 2) ? 1536 : 17920;
  int lw = 7 - sc, W = 1 << lw;
  int lS = 14 - 2 * sc;
  int N = 8 << (2 * sc);
  int Kpad = (sc < 2) ? 32 : N;
  int WC = 1 << logWC;
  int d0 = bx * (WC * 64);
  int nb = by * (WR * 16);
  __shared__ __align__(16) unsigned short As[2][64][40];
  __shared__ __align__(16) unsigned short Bt[2][256][32];
  int tid = threadIdx.x;
  int w = tid >> 6, l = tid & 63;
  int wr = w >> logWC, wc = w & (WC - 1);
  int l15 = l & 15, lhi = l >> 4;
  floatx4 zf = {0.f, 0.f, 0.f, 0.f};
  floatx4 acc[4];
#pragma unroll
  for (int i = 0; i < 4; ++i) acc[i] = zf;
  int bmp = tid & 15;
  int dg = tid >> 4;
  bool act0 = (WC > 1) || (dg < 8);
  bool has1 = (WC == 4);
  bool doA = tid < WR * 64;
  int arow = tid >> 2, akg = (tid & 3) * 8;
  int ksteps = Kpad >> 5;
  uintx4 zu = {0u, 0u, 0u, 0u};
  int vcb = (512 + sc * 64) * 65536;
  uintx4 av = zu, lo0 = zu, hi0 = zu, lo1 = zu, hi1 = zu;
#define PLOADS(KS) { int k0 = (KS) * 32; \
    av = zu; lo0 = zu; hi0 = zu; lo1 = zu; hi1 = zu; \
    if (doA) av = *(const uintx4*)(pbuf + poff + (nb + arow) * Kpad + k0 + akg); \
    int gm0 = k0 + 2 * bmp, gm1 = gm0 + 1; \
    bool mv0 = gm0 < N, mv1 = gm1 < N; \
    int pt0 = 0, sp00 = 0, pt1 = 0, sp01 = 0; \
    if (mv0) patch_row(gm0, sc, lw, pt0, sp00); \
    if (mv1) patch_row(gm1, sc, lw, pt1, sp01); \
    { int d = d0 + dg * 8; int cl = d >> lS; int s = d & ((1 << lS) - 1); \
      int hh = s >> lw, ww = s & (W - 1); int sp = (hh << 8) + ww; \
      if (act0 && mv0) lo0 = *(const uintx4*)(qkv + pt0 * 768 * 65536 + vcb + cl * 65536 + sp00 + sp); \
      if (act0 && mv1) hi0 = *(const uintx4*)(qkv + pt1 * 768 * 65536 + vcb + cl * 65536 + sp01 + sp); } \
    if (has1) { int d = d0 + (dg + 16) * 8; int cl = d >> lS; int s = d & ((1 << lS) - 1); \
      int hh = s >> lw, ww = s & (W - 1); int sp = (hh << 8) + ww; \
      if (mv0) lo1 = *(const uintx4*)(qkv + pt0 * 768 * 65536 + vcb + cl * 65536 + sp00 + sp); \
      if (mv1) hi1 = *(const uintx4*)(qkv + pt1 * 768 * 65536 + vcb + cl * 65536 + sp01 + sp); } }
  PLOADS(0);
  for (int ks = 0; ks < ksteps; ++ks) {
    int b = ks & 1;
    if (doA) *(uintx4*)&As[b][arow][akg] = av;
    if (act0) {
      int du = dg * 8;
#pragma unroll
      for (int j = 0; j < 8; ++j) {
        int d = du + j;
        unsigned losh = (lo0[j >> 1] >> ((j & 1) * 16)) & 0xFFFFu;
        unsigned hish = (hi0[j >> 1] >> ((j & 1) * 16)) & 0xFFFFu;
        unsigned wv = losh | (hish << 16);
        int slot = (bmp >> 2) ^ ((d >> 1) & 3) ^ ((d >> 3) & 3);
        ((unsigned int*)&Bt[b][d][0])[slot * 4 + (bmp & 3)] = wv;
      }
    }
    if (has1) {
      int du = (dg + 16) * 8;
#pragma unroll
      for (int j = 0; j < 8; ++j) {
        int d = du + j;
        unsigned losh = (lo1[j >> 1] >> ((j & 1) * 16)) & 0xFFFFu;
        unsigned hish = (hi1[j >> 1] >> ((j & 1) * 16)) & 0xFFFFu;
        unsigned wv = losh | (hish << 16);
        int slot = (bmp >> 2) ^ ((d >> 1) & 3) ^ ((d >> 3) & 3);
        ((unsigned int*)&Bt[b][d][0])[slot * 4 + (bmp & 3)] = wv;
      }
    }
    __syncthreads();
    if (ks + 1 < ksteps) PLOADS(ks + 1);
    short8 a = *(const short8*)&As[b][wr * 16 + l15][lhi * 8];
    __builtin_amdgcn_s_setprio(1);
#pragma unroll
    for (int fn = 0; fn < 4; ++fn) {
      int row = wc * 64 + fn * 16 + l15;
      int slot = lhi ^ ((row >> 1) & 3) ^ ((row >> 3) & 3);
      short8 bb = *(const short8*)&Bt[b][row][slot * 8];
      acc[fn] = __builtin_amdgcn_mfma_f32_16x16x32_bf16(a, bb, acc[fn], 0, 0, 0);
    }
    __builtin_amdgcn_s_setprio(0);
  }
#undef PLOADS
  int nrow = nb + wr * 16 + lhi * 4;
#pragma unroll
  for (int rr = 0; rr < 4; ++rr) {
    int n = nrow + rr;
    if (n < N) {
      int pt, sp0;
      patch_row(n, sc, lw, pt, sp0);
#pragma unroll
      for (int fn = 0; fn < 4; ++fn) {
        int d = d0 + wc * 64 + fn * 16 + l15;
        int cl = d >> lS;
        int s = d & ((1 << lS) - 1);
        int hh = s >> lw, ww = s & (W - 1);
        int c = sc * 64 + cl;
        ynat[(pt * 256 + c) * 65536 + sp0 + (hh << 8) + ww] = f2bf(acc[fn][rr]);
      }
    }
  }
}

// ---------------- conv3x3: halo-row staging (R9 + T5 setprio) ----------------
__global__ __launch_bounds__(256, 2) void k_conv(const unsigned short* __restrict__ yt,
                                                 const unsigned short* __restrict__ wo,
                                                 const float* __restrict__ bo,
                                                 float* __restrict__ out) {
  __shared__ __align__(16) unsigned short As[128][128];
  __shared__ __align__(16) unsigned short Bs[130][64];
  int flat = blockIdx.x;
  int lg = ((flat & 7) << 7) + (flat >> 3);
  int n_t = lg >> 1, m_t = lg & 1;
  int n0 = n_t << 8, m0 = m_t << 7;
  int tt = n0 >> 16, yy = (n0 >> 8) & 255;
  int tid = threadIdx.x;
  int w = tid >> 6, l = tid & 63;
  int wr = w >> 1, wc = w & 1;
  int l15 = l & 15, lhi = l >> 4;
  int a_d0 = tid >> 7, a_o0 = tid & 127;
  bool doA1 = tid < 128;
  bool doBh = tid >= 254;
  floatx4 zf = {0.f, 0.f, 0.f, 0.f};
  floatx4 acc[4][8];
#pragma unroll
  for (int i = 0; i < 4; ++i)
#pragma unroll
    for (int j = 0; j < 8; ++j) acc[i][j] = zf;
  uintx4 zu = {0u, 0u, 0u, 0u};
  uintx4 rb[4], ra0[4], ra1[4];
  const unsigned short* ybase = yt + (tt << 24);
#define CLOAD(ST) { \
    int dy = (ST) >> 3, cc = ((ST) & 7) << 5; \
    int yq = yy + dy - 1; \
    bool yv = (unsigned)yq < 256u; \
    { int xq = tid - 1; \
      if (yv && (unsigned)xq < 256u) { \
        const uintx4* p = (const uintx4*)(ybase + ((yq << 8) + xq) * 256 + cc); \
        rb[0] = p[0]; rb[1] = p[1]; rb[2] = p[2]; rb[3] = p[3]; \
      } else { rb[0] = zu; rb[1] = zu; rb[2] = zu; rb[3] = zu; } } \
    { const uintx4* p = (const uintx4*)(wo + (dy * 3 + a_d0) * 65536 + (m0 + a_o0) * 256 + cc); \
      ra0[0] = p[0]; ra0[1] = p[1]; ra0[2] = p[2]; ra0[3] = p[3]; } \
    if (doA1) { \
      const uintx4* p = (const uintx4*)(wo + (dy * 3 + 2) * 65536 + (m0 + tid) * 256 + cc); \
      ra1[0] = p[0]; ra1[1] = p[1]; ra1[2] = p[2]; ra1[3] = p[3]; \
    } else if (doBh) { \
      int xq = tid + 1; \
      if (yv && xq < 256) { \
        const uintx4* p = (const uintx4*)(ybase + ((yq << 8) + xq) * 256 + cc); \
        ra1[0] = p[0]; ra1[1] = p[1]; ra1[2] = p[2]; ra1[3] = p[3]; \
      } else { ra1[0] = zu; ra1[1] = zu; ra1[2] = zu; ra1[3] = zu; } } }
  CLOAD(0);
  for (int st = 0; st < 24; ++st) {
    __syncthreads();
    {
      int brow = tid >> 1, bhf = (tid & 1) * 4, br7 = brow & 7;
#pragma unroll
      for (int j = 0; j < 4; ++j)
        *(uintx4*)&Bs[brow][((bhf + j) ^ br7) * 8] = rb[j];
      int ao7 = a_o0 & 7;
#pragma unroll
      for (int j = 0; j < 4; ++j)
        *(uintx4*)&As[a_o0][((a_d0 * 4 + j) ^ ao7) * 8] = ra0[j];
      if (doA1) {
        int o7 = tid & 7;
#pragma unroll
        for (int j = 0; j < 4; ++j)
          *(uintx4*)&As[tid][((8 + j) ^ o7) * 8] = ra1[j];
      } else if (doBh) {
        int xh = tid + 2;
        int brow2 = xh >> 1, bhf2 = (xh & 1) * 4, br72 = brow2 & 7;
#pragma unroll
        for (int j = 0; j < 4; ++j)
          *(uintx4*)&Bs[brow2][((bhf2 + j) ^ br72) * 8] = ra1[j];
      }
    }
    __syncthreads();
    if (st < 23) CLOAD(st + 1);
#pragma unroll
    for (int dx = 0; dx < 3; ++dx) {
      short8 af[4];
#pragma unroll
      for (int f = 0; f < 4; ++f) {
        int ol = wr * 64 + f * 16 + l15;
        af[f] = *(const short8*)&As[ol][((dx * 4 + lhi) ^ (ol & 7)) * 8];
      }
      __builtin_amdgcn_s_setprio(1);
#pragma unroll
      for (int fn = 0; fn < 8; ++fn) {
        int xh = wc * 128 + fn * 16 + l15 + dx;
        short8 b = *(const short8*)&Bs[xh >> 1][((((xh & 1) * 4 + lhi)) ^ ((xh >> 1) & 7)) * 8];
#pragma unroll
        for (int fm = 0; fm < 4; ++fm)
          acc[fm][fn] = __builtin_amdgcn_mfma_f32_16x16x32_bf16(af[fm], b, acc[fm][fn], 0, 0, 0);
      }
      __builtin_amdgcn_s_setprio(0);
    }
  }
#undef CLOAD
#pragma unroll
  for (int fm = 0; fm < 4; ++fm) {
    int o = m0 + wr * 64 + fm * 16 + lhi * 4;
#pragma unroll
    for (int rr = 0; rr < 4; ++rr) {
      float bias = bo[o + rr];
#pragma unroll
      for (int fn = 0; fn < 8; ++fn) {
        int xcol = wc * 128 + fn * 16 + l15;
        float z = acc[fm][fn][rr] + bias;
        out[((tt * 256 + o + rr) << 16) + (yy << 8) + xcol] = z > 0.f ? z : 0.2f * z;
      }
    }
  }
}

// ---------------------------------------------------------------------------
extern "C" void kernel_launch(void* const* d_in, const int* in_sizes, int n_in,
                              void* d_out, int out_size, void* d_ws, size_t ws_size,
                              hipStream_t stream) {
  const float* x   = (const float*)d_in[0];
  const float* m   = (const float*)d_in[1];
  const float* Wq  = (const float*)d_in[2];
  const float* bq  = (const float*)d_in[3];
  const float* Wk  = (const float*)d_in[4];
  const float* bk  = (const float*)d_in[5];
  const float* Wv  = (const float*)d_in[6];
  const float* bv  = (const float*)d_in[7];
  const float* Wmq = (const float*)d_in[8];
  const float* bmq = (const float*)d_in[9];
  const float* Wmk = (const float*)d_in[10];
  const float* bmk = (const float*)d_in[11];
  const float* Wo  = (const float*)d_in[12];
  const float* bo  = (const float*)d_in[13];

  char* ws = (char*)d_ws;
  unsigned short* qkv   = (unsigned short*)(ws);
  unsigned short* xtb   = (unsigned short*)(ws + 201326592);  // xt, later yt
  unsigned short* wqkv  = (unsigned short*)(ws + 268435456);
  unsigned short* wobf  = (unsigned short*)(ws + 268828672);
  float* bias           = (float*)(ws + 270008320);
  float* msc            = (float*)(ws + 270011392);
  float* scores         = (float*)(ws + 270011456);
  float* G              = (float*)(ws + 271129920);
  float* rbuf           = (float*)(ws + 272248384);
  unsigned short* pbuf  = (unsigned short*)(ws + 272251104);
  float* out            = (float*)d_out;
  unsigned short* ynat  = (unsigned short*)d_out;  // low half of d_out as bf16 scratch

  k_prep<<<dim3(5258), dim3(256), 0, stream>>>(Wq, Wk, Wv, bq, bk, bv, Wmq, bmq, Wmk, bmk,
                                               Wo, wqkv, bias, msc, wobf, scores,
                                               (unsigned int*)pbuf);
  k_xtm<<<dim3(8690), dim3(256), 0, stream>>>(x, xtb, m, G, rbuf);
  k_qkv<<<dim3(3072), dim3(256), 49152, stream>>>(xtb, wqkv, bias, qkv);
  k_scores_all<<<dim3(480), dim3(256), 0, stream>>>(qkv, scores);
  k_softmax<<<dim3(680), dim3(64), 0, stream>>>(scores, G, rbuf, msc, pbuf);
  k_pv<<<dim3(10240), dim3(256), 0, stream>>>(qkv, pbuf, ynat);
  k_yt<<<dim3(1024, 4, 2), dim3(256), 0, stream>>>(ynat, xtb);
  k_conv<<<dim3(1024), dim3(256), 0, stream>>>(xtb, wobf, bo, out);
}